// Round 6
// baseline (218.700 us; speedup 1.0000x reference)
//
#include <hip/hip_runtime.h>
#include <hip/hip_bf16.h>

#define Bn 4
#define Tn 256
#define Un 64
#define UP1 65
#define Vn 1024
#define Dn 256
#define Hn 256
#define BLANKC 1023
#define NEGF (-1.0e30f)
#define CTCW 0.3f

typedef __attribute__((ext_vector_type(8))) short short8;
typedef __attribute__((ext_vector_type(4))) float f32x4;
typedef __attribute__((ext_vector_type(4))) unsigned int u32x4;

#define GLD_LDS16(gp, lp)                                                      \
  __builtin_amdgcn_global_load_lds(                                            \
      (const __attribute__((address_space(1))) void*)(gp),                     \
      (__attribute__((address_space(3))) void*)(lp), 16, 0, 0)

static __device__ __forceinline__ unsigned short f2bf(float f) {
  unsigned int u = __float_as_uint(f);
  u += 0x7FFFu + ((u >> 16) & 1u);
  return (unsigned short)(u >> 16);
}
static __device__ __forceinline__ unsigned int pack2bf(float a, float b) {
  return (unsigned int)f2bf(a) | ((unsigned int)f2bf(b) << 16);
}
static __device__ __forceinline__ float ftanh(float x) {
  float e = __expf(2.0f * x);
  return 1.0f - 2.0f / (e + 1.0f);
}
static __device__ __forceinline__ float laddexp(float a, float b) {
  float m = fmaxf(a, b), n = fminf(a, b);
  return m + __logf(1.0f + __expf(n - m));
}
static __device__ __forceinline__ float laddexp3(float a, float b, float c) {
  float m = fmaxf(fmaxf(a, b), c);
  return m + __logf(__expf(a - m) + __expf(b - m) + __expf(c - m));
}
// lane i <- lane i-1 (lane 0 gets 0; callers override lane 0). DPP wave_shr:1.
static __device__ __forceinline__ float shfl_up1(float x) {
  int r = __builtin_amdgcn_update_dpp(0, __float_as_int(x), 0x138, 0xF, 0xF, false);
  return __int_as_float(r);
}

// ---------------------------------------------------------------------------
// K1 k_prep: bf16 transposes of all four W matrices + zero d_out.
// ---------------------------------------------------------------------------
__global__ __launch_bounds__(256) void k_prep(
    const float* __restrict__ W_enc, const float* __restrict__ W_dec,
    const float* __restrict__ W_out, const float* __restrict__ W_ctc,
    unsigned short* __restrict__ Wt_enc, unsigned short* __restrict__ Wt_dec,
    unsigned short* __restrict__ Wt_out, unsigned short* __restrict__ Wt_ctc,
    float* __restrict__ out) {
  const int blk = blockIdx.x, tid = threadIdx.x;
  if (blk == 0 && tid == 0) out[0] = 0.0f;
  const float* Wsrc;
  unsigned short* Wd;
  int tt, ld;
  if (blk < 64) {
    Wsrc = W_out; Wd = Wt_out; tt = blk; ld = 1024;
  } else if (blk < 128) {
    Wsrc = W_ctc; Wd = Wt_ctc; tt = blk - 64; ld = 1024;
  } else if (blk < 144) {
    Wsrc = W_enc; Wd = Wt_enc; tt = blk - 128; ld = 256;
  } else {
    Wsrc = W_dec; Wd = Wt_dec; tt = blk - 144; ld = 256;
  }
  const int k0 = (tt & 3) * 64, v0 = (tt >> 2) * 64;
  __shared__ float tilebuf[64][65];
#pragma unroll
  for (int rep = 0; rep < 16; ++rep) {
    int e = rep * 256 + tid;
    int rr = e >> 6, cc = e & 63;
    tilebuf[rr][cc] = Wsrc[(k0 + rr) * ld + (v0 + cc)];
  }
  __syncthreads();
#pragma unroll
  for (int rep = 0; rep < 16; ++rep) {
    int e = rep * 256 + tid;
    int rr = e >> 6, cc = e & 63;  // rr: v offset, cc: k offset
    Wd[(v0 + rr) * 256 + (k0 + cc)] = f2bf(tilebuf[cc][rr]);
  }
}

// ---------------------------------------------------------------------------
// K1b k_lin: enc_lin / dec_lin via MFMA (tiny).
// ---------------------------------------------------------------------------
__global__ __launch_bounds__(256) void k_lin(
    const float* __restrict__ x_enc, const float* __restrict__ x_dec,
    const unsigned short* __restrict__ Wt_enc, const float* __restrict__ b_enc,
    const unsigned short* __restrict__ Wt_dec, const float* __restrict__ b_dec,
    float* __restrict__ enc_lin, float* __restrict__ dec_lin) {
  __shared__ __align__(16) char Asw[64 * 512];
  const int tid = threadIdx.x;
  const int w = tid >> 6, l = tid & 63;
  const int l15 = l & 15, l4 = l >> 4;
  const bool enc = blockIdx.x < 16;
  const int m0 = enc ? blockIdx.x * 64 : (blockIdx.x - 16) * 64;
  const int Mlim = enc ? 1024 : 260;
  const float* xp = enc ? x_enc : x_dec;
  const unsigned short* Wt = enc ? Wt_enc : Wt_dec;
  const float* bias = enc ? b_enc : b_dec;
  float* outp = enc ? enc_lin : dec_lin;

#pragma unroll
  for (int it = 0; it < 8; ++it) {
    int e = (it << 8) + tid;
    int i = e >> 5;
    int k0 = (e & 31) << 3;
    int r = m0 + i;
    if (r > Mlim - 1) r = Mlim - 1;
    const float* sp = xp + r * 256 + k0;
    f32x4 e0 = *(const f32x4*)sp;
    f32x4 e1 = *(const f32x4*)(sp + 4);
    u32x4 pv;
    pv[0] = pack2bf(e0[0], e0[1]);
    pv[1] = pack2bf(e0[2], e0[3]);
    pv[2] = pack2bf(e1[0], e1[1]);
    pv[3] = pack2bf(e1[2], e1[3]);
    int byt = (i << 9) + (k0 << 1);
    byt ^= (i & 7) << 4;
    *(u32x4*)(Asw + byt) = pv;
  }
  __syncthreads();

  const int nb = w * 64;
  f32x4 acc[4][4] = {};
#pragma unroll
  for (int ks = 0; ks < 8; ++ks) {
    int k = ks * 32 + l4 * 8;
    short8 af[4];
#pragma unroll
    for (int mt = 0; mt < 4; ++mt) {
      int i = mt * 16 + l15;
      int byt = (i << 9) + (k << 1);
      byt ^= (i & 7) << 4;
      af[mt] = *(const short8*)(Asw + byt);
    }
    short8 bfr[4];
#pragma unroll
    for (int nt = 0; nt < 4; ++nt) {
      int n = nb + nt * 16 + l15;
      bfr[nt] = *(const short8*)(Wt + n * 256 + k);
    }
#pragma unroll
    for (int mt = 0; mt < 4; ++mt)
#pragma unroll
      for (int nt = 0; nt < 4; ++nt)
        acc[mt][nt] = __builtin_amdgcn_mfma_f32_16x16x32_bf16(
            af[mt], bfr[nt], acc[mt][nt], 0, 0, 0);
  }
  float biasv[4];
#pragma unroll
  for (int nt = 0; nt < 4; ++nt) biasv[nt] = bias[nb + nt * 16 + l15];
#pragma unroll
  for (int mt = 0; mt < 4; ++mt)
#pragma unroll
    for (int rr = 0; rr < 4; ++rr) {
      int row = m0 + mt * 16 + l4 * 4 + rr;
      if (row < Mlim) {
#pragma unroll
        for (int nt = 0; nt < 4; ++nt)
          outp[row * 256 + nb + nt * 16 + l15] = acc[mt][nt][rr] + biasv[nt];
      }
    }
}

// ---------------------------------------------------------------------------
// K2 merged: blocks 0-15 = CTC head; blocks 16-1055 = joiner.
// B staged per (c,ks)-step via global_load_lds into a [sub=k/8][col] layout:
// each lane's 4 rounds consume one FULL 64B line of Wt (4x less L2 line
// traffic than strided-16B), LDS reads are l15-contiguous (conflict-free).
// 2-phase loop: stage(next buf) -> ds_read cur + 16 MFMA -> barrier.
// ---------------------------------------------------------------------------
__global__ __launch_bounds__(256, 2) void k_join2(
    const float* __restrict__ enc_lin, const float* __restrict__ dec_lin,
    const unsigned short* __restrict__ Wt_out, const float* __restrict__ b_out,
    const float* __restrict__ x_enc,
    const unsigned short* __restrict__ Wt_ctc, const float* __restrict__ b_ctc,
    const int* __restrict__ target,
    float* __restrict__ lp_blank, float* __restrict__ lp_label,
    float* __restrict__ ctc_blank, float* __restrict__ ctc_lse,
    float* __restrict__ ctc_lab) {
  __shared__ __align__(16) char Asw[64 * 512];    // 32KB A tile
  __shared__ __align__(16) char Bsw[2 * 16384];   // 2 x 16KB B step buffers
  __shared__ float s_psum[4][64];
  __shared__ float s_blank[64], s_label[64];
  __shared__ int s_tgt[64];

  const int tid = threadIdx.x;
  const int w = tid >> 6, l = tid & 63;
  const int l15 = l & 15, l4 = l >> 4;

  const bool joiner = blockIdx.x >= 16;
  const unsigned short* Wt = joiner ? Wt_out : Wt_ctc;
  const float* bias = joiner ? b_out : b_ctc;

  // Per (c,ks)-step: unit(sub,col) = Wt[(c*256+col)*256 + ks*32 + sub*8 ..+8]
  // at LDS byte sub*4096 + col*16. gload_lds dst = uniform base + lane*16:
  // round r, wave w -> base r*4096 + w*1024 => (sub=r, col=tid).
  auto stageB = [&](int cc, int kss, int buf) {
#pragma unroll
    for (int r = 0; r < 4; ++r) {
      const unsigned short* src = Wt + cc * 65536 + tid * 256 + kss * 32 + r * 8;
      GLD_LDS16(src, Bsw + buf * 16384 + r * 4096 + (w << 10));
    }
  };

  int b, r0 = 0, g0 = 0;
  if (joiner) {
    const int bid = blockIdx.x - 16;
    b = bid / 260;
    r0 = (bid % 260) * 64;
#pragma unroll
    for (int it = 0; it < 8; ++it) {
      int e = (it << 8) + tid;
      int i = e >> 5;
      int k0 = (e & 31) << 3;
      int r = r0 + i;
      int t = r / 65;
      int u = r - t * 65;
      const float* ep = enc_lin + ((b * Tn + t) * Hn + k0);
      const float* dp = dec_lin + ((b * UP1 + u) * Hn + k0);
      f32x4 e0 = *(const f32x4*)ep;
      f32x4 e1 = *(const f32x4*)(ep + 4);
      f32x4 d0 = *(const f32x4*)dp;
      f32x4 d1 = *(const f32x4*)(dp + 4);
      u32x4 pv;
      pv[0] = pack2bf(ftanh(e0[0] + d0[0]), ftanh(e0[1] + d0[1]));
      pv[1] = pack2bf(ftanh(e0[2] + d0[2]), ftanh(e0[3] + d0[3]));
      pv[2] = pack2bf(ftanh(e1[0] + d1[0]), ftanh(e1[1] + d1[1]));
      pv[3] = pack2bf(ftanh(e1[2] + d1[2]), ftanh(e1[3] + d1[3]));
      int byt = (i << 9) + (k0 << 1);
      byt ^= (i & 7) << 4;
      *(u32x4*)(Asw + byt) = pv;
    }
    if (tid < 64) {
      int u = (r0 + tid) % 65;
      s_tgt[tid] = (u < Un) ? target[b * Un + u] : -1;
    }
  } else {
    g0 = blockIdx.x * 64;
    b = g0 >> 8;
#pragma unroll
    for (int it = 0; it < 8; ++it) {
      int e = (it << 8) + tid;
      int i = e >> 5;
      int k0 = (e & 31) << 3;
      const float* sp = x_enc + (g0 + i) * Dn + k0;
      f32x4 e0 = *(const f32x4*)sp;
      f32x4 e1 = *(const f32x4*)(sp + 4);
      u32x4 pv;
      pv[0] = pack2bf(e0[0], e0[1]);
      pv[1] = pack2bf(e0[2], e0[3]);
      pv[2] = pack2bf(e1[0], e1[1]);
      pv[3] = pack2bf(e1[2], e1[3]);
      int byt = (i << 9) + (k0 << 1);
      byt ^= (i & 7) << 4;
      *(u32x4*)(Asw + byt) = pv;
    }
    if (tid < 64) s_tgt[tid] = target[b * Un + tid];
  }
  stageB(0, 0, 0);
  __syncthreads();  // drains LDS writes (A) + vmcnt (B step 0)

  float ssum[16];
#pragma unroll
  for (int j = 0; j < 16; ++j) ssum[j] = 0.0f;

#pragma unroll 1
  for (int c = 0; c < 4; ++c) {
    const int nb = c * 256 + w * 64;
    f32x4 acc[4][4] = {};
#pragma unroll
    for (int ks = 0; ks < 8; ++ks) {
      if (ks < 7) stageB(c, ks + 1, (ks + 1) & 1);
      else if (c < 3) stageB(c + 1, 0, 0);
      const int k = ks * 32 + l4 * 8;
      short8 af[4];
#pragma unroll
      for (int mt = 0; mt < 4; ++mt) {
        int i = mt * 16 + l15;
        int byt = (i << 9) + (k << 1);
        byt ^= (i & 7) << 4;
        af[mt] = *(const short8*)(Asw + byt);
      }
      short8 bfr[4];
#pragma unroll
      for (int nt = 0; nt < 4; ++nt) {
        int byt = (ks & 1) * 16384 + l4 * 4096 + (w * 64 + nt * 16 + l15) * 16;
        bfr[nt] = *(const short8*)(Bsw + byt);
      }
#pragma unroll
      for (int mt = 0; mt < 4; ++mt)
#pragma unroll
        for (int nt = 0; nt < 4; ++nt)
          acc[mt][nt] = __builtin_amdgcn_mfma_f32_16x16x32_bf16(
              af[mt], bfr[nt], acc[mt][nt], 0, 0, 0);
      __syncthreads();  // next buffer ready
    }
    float biasv[4];
#pragma unroll
    for (int nt = 0; nt < 4; ++nt) biasv[nt] = bias[nb + nt * 16 + l15];
#pragma unroll
    for (int mt = 0; mt < 4; ++mt)
#pragma unroll
      for (int nt = 0; nt < 4; ++nt)
#pragma unroll
        for (int rr = 0; rr < 4; ++rr) acc[mt][nt][rr] += biasv[nt];

    if (joiner) {
      if (c == 3 && w == 3 && l15 == 15) {
#pragma unroll
        for (int mt = 0; mt < 4; ++mt)
#pragma unroll
          for (int rr = 0; rr < 4; ++rr)
            s_blank[mt * 16 + l4 * 4 + rr] = acc[mt][3][rr];
      }
#pragma unroll
      for (int mt = 0; mt < 4; ++mt)
#pragma unroll
        for (int rr = 0; rr < 4; ++rr) {
          int row = mt * 16 + l4 * 4 + rr;
          int tg = s_tgt[row];
          if ((tg >> 8) == c && ((tg >> 6) & 3) == w && (tg & 15) == l15) {
            int ntv = (tg >> 4) & 3;
            float v01 = (ntv & 1) ? acc[mt][1][rr] : acc[mt][0][rr];
            float v23 = (ntv & 1) ? acc[mt][3][rr] : acc[mt][2][rr];
            s_label[row] = (ntv & 2) ? v23 : v01;
          }
        }
    } else {
      if (c == 3 && w == 3 && l15 == 15) {
#pragma unroll
        for (int mt = 0; mt < 4; ++mt)
#pragma unroll
          for (int rr = 0; rr < 4; ++rr)
            s_blank[mt * 16 + l4 * 4 + rr] = acc[mt][3][rr];
      }
#pragma unroll 1
      for (int u = 0; u < 64; ++u) {
        int tgu = s_tgt[u];
        if ((tgu >> 8) == c && ((tgu >> 6) & 3) == w) {
          int ntv = (tgu >> 4) & 3;
          if ((tgu & 15) == l15) {
#pragma unroll
            for (int mt = 0; mt < 4; ++mt)
#pragma unroll
              for (int rr = 0; rr < 4; ++rr) {
                float v01 = (ntv & 1) ? acc[mt][1][rr] : acc[mt][0][rr];
                float v23 = (ntv & 1) ? acc[mt][3][rr] : acc[mt][2][rr];
                float v = (ntv & 2) ? v23 : v01;
                ctc_lab[(g0 + mt * 16 + l4 * 4 + rr) * 64 + u] = v;
              }
          }
        }
      }
    }
#pragma unroll
    for (int mt = 0; mt < 4; ++mt)
#pragma unroll
      for (int rr = 0; rr < 4; ++rr)
        ssum[mt * 4 + rr] += __expf(acc[mt][0][rr]) + __expf(acc[mt][1][rr]) +
                             __expf(acc[mt][2][rr]) + __expf(acc[mt][3][rr]);
  }

#pragma unroll
  for (int ms = 1; ms < 16; ms <<= 1)
#pragma unroll
    for (int j = 0; j < 16; ++j) ssum[j] += __shfl_xor(ssum[j], ms, 64);
  if (l15 == 0) {
#pragma unroll
    for (int j = 0; j < 16; ++j)
      s_psum[w][(j >> 2) * 16 + l4 * 4 + (j & 3)] = ssum[j];
  }
  __syncthreads();

  if (tid < 64) {
    float tot = s_psum[0][tid] + s_psum[1][tid] + s_psum[2][tid] + s_psum[3][tid];
    float lse = __logf(tot);
    if (joiner) {
      int r = r0 + tid;
      int t = r / 65;
      int u = r - t * 65;
      lp_blank[(b * Tn + t) * UP1 + u] = s_blank[tid] - lse;
      if (u < Un) lp_label[(b * Tn + t) * Un + u] = s_label[tid] - lse;
    } else {
      ctc_blank[g0 + tid] = s_blank[tid] - lse;
      ctc_lse[g0 + tid] = lse;
    }
  }
}

// ---------------------------------------------------------------------------
// K3 k_dp: blocks 0-3 RNNT anti-diagonal DP; blocks 4-7 CTC DP.
// Branch-free chain: the u=64 track uses lane-uniform broadcast LDS reads and
// is computed on all lanes + cndmask-merged (no divergent branch). sA padded
// to stride 66 (per-lane delta -65 == 1 mod 32 -> conflict-free). All loads
// clamped+unconditional -> hoistable across the unroll-8 body.
// ---------------------------------------------------------------------------
__global__ __launch_bounds__(256) void k_dp(
    const float* __restrict__ lp_blank, const float* __restrict__ lp_label,
    const float* __restrict__ ctc_blank, const float* __restrict__ ctc_lse,
    const float* __restrict__ ctc_lab,
    const int* __restrict__ target,
    const int* __restrict__ flen, const int* __restrict__ tlen,
    float* __restrict__ out) {
  __shared__ float sA[256 * 66];             // RNNT lp_blank[t][u], stride 66
  __shared__ __align__(16) float sB[16384];  // RNNT lp_label / CTC raw labels
  __shared__ float sC[256], sD[256];         // CTC blank / lse
  __shared__ float cT[129];
  const int tid = threadIdx.x;
  const int l = tid & 63;

  if (blockIdx.x < 4) {
    const int b = blockIdx.x;
    for (int i = tid; i < 16640; i += 256) {
      int r = i / 65, cidx = i - r * 65;
      sA[r * 66 + cidx] = lp_blank[b * 16640 + i];
    }
    {
      const f32x4* g2 = (const f32x4*)(lp_label + b * 16384);
      f32x4* s2 = (f32x4*)sB;
      for (int i = tid; i < 4096; i += 256) s2[i] = g2[i];
    }
    __syncthreads();
    if (tid < 64) {
      const int ft = flen[b], tl = tlen[b];
      const int dstar = ft - 1 + tl;
      const int lc = (l >= 1) ? l - 1 : 0;
      float a = (l == 0) ? 0.0f : NEGF;
      float a64 = NEGF, cap = NEGF;
      for (int d0 = 1; d0 <= 313; d0 += 8) {  // d up to 320 >= 319; pad neutral
#pragma unroll
        for (int j = 0; j < 8; ++j) {
          const int d = d0 + j;
          const int t = d - l;
          const int tbc = (t < 1) ? 1 : (t > 255 ? 255 : t);
          const int tcc = (t < 0) ? 0 : (t > 255 ? 255 : t);
          float vb = sA[(tbc - 1) * 66 + l];
          float vl = sB[tcc * 64 + lc];
          const int t64 = d - 64;
          const int t64b = (t64 < 1) ? 1 : (t64 > 255 ? 255 : t64);
          const int t64c = (t64 < 0) ? 0 : (t64 > 255 ? 255 : t64);
          float vb64 = sA[(t64b - 1) * 66 + 64];  // uniform broadcast
          float vl64 = sB[t64c * 64 + 63];        // uniform broadcast
          float aleft = shfl_up1(a);
          bool valid = (t >= 0) && (t < Tn);
          float up = (valid && (t >= 1)) ? (a + vb) : NEGF;
          float lft = (valid && (l >= 1)) ? (aleft + vl) : NEGF;
          float nw = valid ? laddexp(up, lft) : NEGF;
          // u=64 track: all lanes compute, lane 63 keeps (old a = alpha[t64][63])
          float up64 = (t64 >= 1) ? (a64 + vb64) : NEGF;
          float nw64 = laddexp(up64, a + vl64);
          bool s64 = (l == 63) && (t64 >= 0) && (t64 < Tn);
          a = nw;
          a64 = s64 ? nw64 : a64;
          bool hit = (d == dstar);
          cap = (hit && (l == tl)) ? a : cap;
          cap = (hit && (tl == 64) && (l == 63)) ? a64 : cap;
        }
      }
      bool owner = (tl < 64) ? (l == tl) : (l == 63);
      if (owner) atomicAdd(out, -0.25f * (cap + sA[(ft - 1) * 66 + tl]));
    }
  } else {
    const int b = blockIdx.x - 4;
    {
      const f32x4* g2 = (const f32x4*)(ctc_lab + b * 16384);
      f32x4* s2 = (f32x4*)sB;
      for (int i = tid; i < 4096; i += 256) s2[i] = g2[i];
      sC[tid] = ctc_blank[b * 256 + tid];
      sD[tid] = ctc_lse[b * 256 + tid];
    }
    __syncthreads();
    if (tid < 64) {
      const int ft = flen[b], tl = tlen[b];
      const int tg = target[b * Un + l];
      const int tgp = (l >= 1) ? target[b * Un + l - 1] : -1;
      const bool skip1 = (l >= 1) && (tg != tgp);
      float a0 = (l == 0) ? sC[0] : NEGF;
      float a1 = (l == 0) ? (sB[0] - sD[0]) : NEGF;
      float a2 = NEGF;
      for (int t0 = 1; t0 <= 249; t0 += 8) {  // t up to 256; pad frozen
#pragma unroll
        for (int j = 0; j < 8; ++j) {
          const int t = t0 + j;
          const int tc = (t > 255) ? 255 : t;
          float eb = sC[tc];    // uniform broadcast
          float lse = sD[tc];   // uniform broadcast
          float e1 = sB[tc * 64 + l] - lse;
          float pm1 = shfl_up1(a1);
          pm1 = (l == 0) ? NEGF : pm1;
          float n0 = eb + laddexp(a0, pm1);
          float n1 = e1 + laddexp3(a1, a0, skip1 ? pm1 : NEGF);
          float n2 = eb + laddexp(a2, a1);  // all lanes; lane 63 keeps
          bool run = (t < ft);
          a0 = run ? n0 : a0;
          a1 = run ? n1 : a1;
          a2 = (run && (l == 63)) ? n2 : a2;
        }
      }
      cT[2 * l] = a0;
      cT[2 * l + 1] = a1;
      if (l == 63) cT[128] = a2;
      __builtin_amdgcn_s_waitcnt(0);  // intra-wave lgkm drain before readback
      if (l == 0) {
        int sl = 2 * tl;
        float ll = laddexp(cT[sl], cT[sl - 1]);
        float lb = (ll < NEGF * 0.5f) ? 0.0f : -ll;
        atomicAdd(out, CTCW * 0.25f * lb);
      }
    }
  }
}

// ---------------------------------------------------------------------------
extern "C" void kernel_launch(void* const* d_in, const int* in_sizes, int n_in,
                              void* d_out, int out_size, void* d_ws, size_t ws_size,
                              hipStream_t stream) {
  (void)in_sizes; (void)n_in; (void)out_size; (void)ws_size;
  const float* x_enc = (const float*)d_in[0];
  const float* x_dec = (const float*)d_in[1];
  const float* W_enc = (const float*)d_in[2];
  const float* b_enc = (const float*)d_in[3];
  const float* W_dec = (const float*)d_in[4];
  const float* b_dec = (const float*)d_in[5];
  const float* W_out = (const float*)d_in[6];
  const float* b_out = (const float*)d_in[7];
  const float* W_ctc = (const float*)d_in[8];
  const float* b_ctc = (const float*)d_in[9];
  const int* target = (const int*)d_in[10];
  const int* flen = (const int*)d_in[11];
  const int* tlen = (const int*)d_in[12];

  float* ws = (float*)d_ws;
  float* enc_lin = ws;                    // 262144
  float* dec_lin = ws + 262144;           // 66560
  float* lp_blank = ws + 328704;          // 66560
  float* lp_label = ws + 395264;          // 65536
  float* ctc_blank = ws + 460800;         // 1024
  float* ctc_lse = ws + 461824;           // 1024
  float* ctc_lab = ws + 462848;           // 65536
  unsigned short* Wt_out = (unsigned short*)(ws + 528384);  // 262144 bf16
  unsigned short* Wt_ctc = Wt_out + 262144;                 // 262144 bf16
  // Wt_enc/Wt_dec alias lp_blank/lp_label (disjoint lifetimes).
  unsigned short* Wt_enc = (unsigned short*)lp_blank;       // 65536 bf16
  unsigned short* Wt_dec = (unsigned short*)lp_label;       // 65536 bf16
  float* out = (float*)d_out;

  k_prep<<<dim3(160), dim3(256), 0, stream>>>(
      W_enc, W_dec, W_out, W_ctc, Wt_enc, Wt_dec, Wt_out, Wt_ctc, out);
  k_lin<<<dim3(21), dim3(256), 0, stream>>>(
      x_enc, x_dec, Wt_enc, b_enc, Wt_dec, b_dec, enc_lin, dec_lin);
  k_join2<<<dim3(1056), dim3(256), 0, stream>>>(
      enc_lin, dec_lin, Wt_out, b_out, x_enc, Wt_ctc, b_ctc, target,
      lp_blank, lp_label, ctc_blank, ctc_lse, ctc_lab);
  k_dp<<<dim3(8), dim3(64 * 4), 0, stream>>>(
      lp_blank, lp_label, ctc_blank, ctc_lse, ctc_lab, target, flen, tlen, out);
}

// Round 7
// 174.171 us; speedup vs baseline: 1.2557x; 1.2557x over previous
//
#include <hip/hip_runtime.h>
#include <hip/hip_bf16.h>

#define Bn 4
#define Tn 256
#define Un 64
#define UP1 65
#define Vn 1024
#define Dn 256
#define Hn 256
#define BLANKC 1023
#define NEGF (-1.0e30f)
#define CTCW 0.3f

typedef __attribute__((ext_vector_type(8))) short short8;
typedef __attribute__((ext_vector_type(4))) float f32x4;
typedef __attribute__((ext_vector_type(4))) unsigned int u32x4;

#define GLD_LDS16(gp, lp)                                                      \
  __builtin_amdgcn_global_load_lds(                                            \
      (const __attribute__((address_space(1))) void*)(gp),                     \
      (__attribute__((address_space(3))) void*)(lp), 16, 0, 0)

static __device__ __forceinline__ unsigned short f2bf(float f) {
  unsigned int u = __float_as_uint(f);
  u += 0x7FFFu + ((u >> 16) & 1u);
  return (unsigned short)(u >> 16);
}
static __device__ __forceinline__ unsigned int pack2bf(float a, float b) {
  return (unsigned int)f2bf(a) | ((unsigned int)f2bf(b) << 16);
}
static __device__ __forceinline__ float ftanh(float x) {
  float e = __expf(2.0f * x);
  return 1.0f - 2.0f / (e + 1.0f);
}
static __device__ __forceinline__ float laddexp(float a, float b) {
  float m = fmaxf(a, b), n = fminf(a, b);
  return m + __logf(1.0f + __expf(n - m));
}
static __device__ __forceinline__ float laddexp3(float a, float b, float c) {
  float m = fmaxf(fmaxf(a, b), c);
  return m + __logf(__expf(a - m) + __expf(b - m) + __expf(c - m));
}
// lane i <- lane i-1 (lane 0 gets 0; callers override lane 0). DPP wave_shr:1.
static __device__ __forceinline__ float shfl_up1(float x) {
  int r = __builtin_amdgcn_update_dpp(0, __float_as_int(x), 0x138, 0xF, 0xF, false);
  return __int_as_float(r);
}

// ---------------------------------------------------------------------------
// K1 k_prep: W_out/W_ctc -> step-tiled bf16 layout Wt2[(c,ks)][sub][col][8k]
// (so each k_join2 staging step is a LINEAR 16KB chunk); W_enc/W_dec -> flat
// bf16 transpose for k_lin. Also zeroes d_out.
// blocks 0-63: W_out; 64-127: W_ctc; 128-143: W_enc; 144-159: W_dec.
// ---------------------------------------------------------------------------
__global__ __launch_bounds__(256) void k_prep(
    const float* __restrict__ W_enc, const float* __restrict__ W_dec,
    const float* __restrict__ W_out, const float* __restrict__ W_ctc,
    unsigned short* __restrict__ Wt_enc, unsigned short* __restrict__ Wt_dec,
    unsigned short* __restrict__ Wt_out, unsigned short* __restrict__ Wt_ctc,
    float* __restrict__ out) {
  const int blk = blockIdx.x, tid = threadIdx.x;
  if (blk == 0 && tid == 0) out[0] = 0.0f;
  __shared__ float tilebuf[64][65];
  if (blk < 128) {
    const float* Wsrc = (blk < 64) ? W_out : W_ctc;
    unsigned short* Wd = (blk < 64) ? Wt_out : Wt_ctc;
    const int tt = blk & 63;
    const int k0 = (tt & 3) * 64, v0 = (tt >> 2) * 64;
#pragma unroll
    for (int rep = 0; rep < 16; ++rep) {
      int e = rep * 256 + tid;
      int rr = e >> 6, cc = e & 63;  // rr: k-off, cc: n-off
      tilebuf[rr][cc] = Wsrc[(k0 + rr) * 1024 + (v0 + cc)];
    }
    __syncthreads();
#pragma unroll
    for (int rep = 0; rep < 16; ++rep) {
      int e = rep * 256 + tid;
      int nn = e >> 6, kk = e & 63;  // nn: n-off, kk: k-off
      int n = v0 + nn, k = k0 + kk;
      int c = n >> 8, col = n & 255;
      int ks = k >> 5, sub = (k >> 3) & 3, k7 = k & 7;
      Wd[(c * 8 + ks) * 8192 + sub * 2048 + col * 8 + k7] = f2bf(tilebuf[kk][nn]);
    }
  } else {
    const float* Wsrc = (blk < 144) ? W_enc : W_dec;
    unsigned short* Wd = (blk < 144) ? Wt_enc : Wt_dec;
    const int tt = (blk - 128) & 15;
    const int k0 = (tt & 3) * 64, v0 = (tt >> 2) * 64;
#pragma unroll
    for (int rep = 0; rep < 16; ++rep) {
      int e = rep * 256 + tid;
      int rr = e >> 6, cc = e & 63;
      tilebuf[rr][cc] = Wsrc[(k0 + rr) * 256 + (v0 + cc)];
    }
    __syncthreads();
#pragma unroll
    for (int rep = 0; rep < 16; ++rep) {
      int e = rep * 256 + tid;
      int rr = e >> 6, cc = e & 63;  // rr: v offset, cc: k offset
      Wd[(v0 + rr) * 256 + (k0 + cc)] = f2bf(tilebuf[cc][rr]);
    }
  }
}

// ---------------------------------------------------------------------------
// K1b k_lin: enc_lin / dec_lin via MFMA (tiny; flat-transposed W).
// ---------------------------------------------------------------------------
__global__ __launch_bounds__(256) void k_lin(
    const float* __restrict__ x_enc, const float* __restrict__ x_dec,
    const unsigned short* __restrict__ Wt_enc, const float* __restrict__ b_enc,
    const unsigned short* __restrict__ Wt_dec, const float* __restrict__ b_dec,
    float* __restrict__ enc_lin, float* __restrict__ dec_lin) {
  __shared__ __align__(16) char Asw[64 * 512];
  const int tid = threadIdx.x;
  const int w = tid >> 6, l = tid & 63;
  const int l15 = l & 15, l4 = l >> 4;
  const bool enc = blockIdx.x < 16;
  const int m0 = enc ? blockIdx.x * 64 : (blockIdx.x - 16) * 64;
  const int Mlim = enc ? 1024 : 260;
  const float* xp = enc ? x_enc : x_dec;
  const unsigned short* Wt = enc ? Wt_enc : Wt_dec;
  const float* bias = enc ? b_enc : b_dec;
  float* outp = enc ? enc_lin : dec_lin;

#pragma unroll
  for (int it = 0; it < 8; ++it) {
    int e = (it << 8) + tid;
    int i = e >> 5;
    int k0 = (e & 31) << 3;
    int r = m0 + i;
    if (r > Mlim - 1) r = Mlim - 1;
    const float* sp = xp + r * 256 + k0;
    f32x4 e0 = *(const f32x4*)sp;
    f32x4 e1 = *(const f32x4*)(sp + 4);
    u32x4 pv;
    pv[0] = pack2bf(e0[0], e0[1]);
    pv[1] = pack2bf(e0[2], e0[3]);
    pv[2] = pack2bf(e1[0], e1[1]);
    pv[3] = pack2bf(e1[2], e1[3]);
    int byt = (i << 9) + (k0 << 1);
    byt ^= (i & 7) << 4;
    *(u32x4*)(Asw + byt) = pv;
  }
  __syncthreads();

  const int nb = w * 64;
  f32x4 acc[4][4] = {};
#pragma unroll
  for (int ks = 0; ks < 8; ++ks) {
    int k = ks * 32 + l4 * 8;
    short8 af[4];
#pragma unroll
    for (int mt = 0; mt < 4; ++mt) {
      int i = mt * 16 + l15;
      int byt = (i << 9) + (k << 1);
      byt ^= (i & 7) << 4;
      af[mt] = *(const short8*)(Asw + byt);
    }
    short8 bfr[4];
#pragma unroll
    for (int nt = 0; nt < 4; ++nt) {
      int n = nb + nt * 16 + l15;
      bfr[nt] = *(const short8*)(Wt + n * 256 + k);
    }
#pragma unroll
    for (int mt = 0; mt < 4; ++mt)
#pragma unroll
      for (int nt = 0; nt < 4; ++nt)
        acc[mt][nt] = __builtin_amdgcn_mfma_f32_16x16x32_bf16(
            af[mt], bfr[nt], acc[mt][nt], 0, 0, 0);
  }
  float biasv[4];
#pragma unroll
  for (int nt = 0; nt < 4; ++nt) biasv[nt] = bias[nb + nt * 16 + l15];
#pragma unroll
  for (int mt = 0; mt < 4; ++mt)
#pragma unroll
    for (int rr = 0; rr < 4; ++rr) {
      int row = m0 + mt * 16 + l4 * 4 + rr;
      if (row < Mlim) {
#pragma unroll
        for (int nt = 0; nt < 4; ++nt)
          outp[row * 256 + nb + nt * 16 + l15] = acc[mt][nt][rr] + biasv[nt];
      }
    }
}

// ---------------------------------------------------------------------------
// K2 merged: blocks 0-15 = CTC head; blocks 16-1055 = joiner.
// B staged per (c,ks)-step from the step-tiled Wt2: each step is a LINEAR
// 16KB global->LDS copy (lane addr = base + tid*16 -> fully coalesced, 16
// requests/instr instead of 64). 2-phase: stage(next) -> ds_read+MFMA -> bar.
// ---------------------------------------------------------------------------
__global__ __launch_bounds__(256, 2) void k_join2(
    const float* __restrict__ enc_lin, const float* __restrict__ dec_lin,
    const unsigned short* __restrict__ Wt_out, const float* __restrict__ b_out,
    const float* __restrict__ x_enc,
    const unsigned short* __restrict__ Wt_ctc, const float* __restrict__ b_ctc,
    const int* __restrict__ target,
    float* __restrict__ lp_blank, float* __restrict__ lp_label,
    float* __restrict__ ctc_blank, float* __restrict__ ctc_lse,
    float* __restrict__ ctc_lab) {
  __shared__ __align__(16) char Asw[64 * 512];    // 32KB A tile
  __shared__ __align__(16) char Bsw[2 * 16384];   // 2 x 16KB B step buffers
  __shared__ float s_psum[4][64];
  __shared__ float s_blank[64], s_label[64];
  __shared__ int s_tgt[64];

  const int tid = threadIdx.x;
  const int w = tid >> 6, l = tid & 63;
  const int l15 = l & 15, l4 = l >> 4;

  const bool joiner = blockIdx.x >= 16;
  const unsigned short* Wt = joiner ? Wt_out : Wt_ctc;
  const float* bias = joiner ? b_out : b_ctc;

  // step (c,ks) = linear chunk Wt2 + (c*8+ks)*8192, 16384 bytes.
  // LDS byte = r*4096 + tid*16 <-> element r*2048 + tid*8 (same linear order).
  auto stageB = [&](int cc, int kss, int buf) {
    const unsigned short* base = Wt + (cc * 8 + kss) * 8192 + tid * 8;
#pragma unroll
    for (int r = 0; r < 4; ++r)
      GLD_LDS16(base + r * 2048, Bsw + buf * 16384 + r * 4096 + (w << 10));
  };

  int b, r0 = 0, g0 = 0;
  if (joiner) {
    const int bid = blockIdx.x - 16;
    b = bid / 260;
    r0 = (bid % 260) * 64;
#pragma unroll
    for (int it = 0; it < 8; ++it) {
      int e = (it << 8) + tid;
      int i = e >> 5;
      int k0 = (e & 31) << 3;
      int r = r0 + i;
      int t = r / 65;
      int u = r - t * 65;
      const float* ep = enc_lin + ((b * Tn + t) * Hn + k0);
      const float* dp = dec_lin + ((b * UP1 + u) * Hn + k0);
      f32x4 e0 = *(const f32x4*)ep;
      f32x4 e1 = *(const f32x4*)(ep + 4);
      f32x4 d0 = *(const f32x4*)dp;
      f32x4 d1 = *(const f32x4*)(dp + 4);
      u32x4 pv;
      pv[0] = pack2bf(ftanh(e0[0] + d0[0]), ftanh(e0[1] + d0[1]));
      pv[1] = pack2bf(ftanh(e0[2] + d0[2]), ftanh(e0[3] + d0[3]));
      pv[2] = pack2bf(ftanh(e1[0] + d1[0]), ftanh(e1[1] + d1[1]));
      pv[3] = pack2bf(ftanh(e1[2] + d1[2]), ftanh(e1[3] + d1[3]));
      int byt = (i << 9) + (k0 << 1);
      byt ^= (i & 7) << 4;
      *(u32x4*)(Asw + byt) = pv;
    }
    if (tid < 64) {
      int u = (r0 + tid) % 65;
      s_tgt[tid] = (u < Un) ? target[b * Un + u] : -1;
    }
  } else {
    g0 = blockIdx.x * 64;
    b = g0 >> 8;
#pragma unroll
    for (int it = 0; it < 8; ++it) {
      int e = (it << 8) + tid;
      int i = e >> 5;
      int k0 = (e & 31) << 3;
      const float* sp = x_enc + (g0 + i) * Dn + k0;
      f32x4 e0 = *(const f32x4*)sp;
      f32x4 e1 = *(const f32x4*)(sp + 4);
      u32x4 pv;
      pv[0] = pack2bf(e0[0], e0[1]);
      pv[1] = pack2bf(e0[2], e0[3]);
      pv[2] = pack2bf(e1[0], e1[1]);
      pv[3] = pack2bf(e1[2], e1[3]);
      int byt = (i << 9) + (k0 << 1);
      byt ^= (i & 7) << 4;
      *(u32x4*)(Asw + byt) = pv;
    }
    if (tid < 64) s_tgt[tid] = target[b * Un + tid];
  }
  stageB(0, 0, 0);
  __syncthreads();  // drains LDS writes (A) + vmcnt (B step 0)

  float ssum[16];
#pragma unroll
  for (int j = 0; j < 16; ++j) ssum[j] = 0.0f;

#pragma unroll 1
  for (int c = 0; c < 4; ++c) {
    const int nb = c * 256 + w * 64;
    f32x4 acc[4][4] = {};
#pragma unroll
    for (int ks = 0; ks < 8; ++ks) {
      if (ks < 7) stageB(c, ks + 1, (ks + 1) & 1);
      else if (c < 3) stageB(c + 1, 0, 0);
      const int k = ks * 32 + l4 * 8;
      short8 af[4];
#pragma unroll
      for (int mt = 0; mt < 4; ++mt) {
        int i = mt * 16 + l15;
        int byt = (i << 9) + (k << 1);
        byt ^= (i & 7) << 4;
        af[mt] = *(const short8*)(Asw + byt);
      }
      short8 bfr[4];
#pragma unroll
      for (int nt = 0; nt < 4; ++nt) {
        int byt = (ks & 1) * 16384 + l4 * 4096 + (w * 64 + nt * 16 + l15) * 16;
        bfr[nt] = *(const short8*)(Bsw + byt);
      }
#pragma unroll
      for (int mt = 0; mt < 4; ++mt)
#pragma unroll
        for (int nt = 0; nt < 4; ++nt)
          acc[mt][nt] = __builtin_amdgcn_mfma_f32_16x16x32_bf16(
              af[mt], bfr[nt], acc[mt][nt], 0, 0, 0);
      __syncthreads();  // next buffer ready
    }
    float biasv[4];
#pragma unroll
    for (int nt = 0; nt < 4; ++nt) biasv[nt] = bias[nb + nt * 16 + l15];
#pragma unroll
    for (int mt = 0; mt < 4; ++mt)
#pragma unroll
      for (int nt = 0; nt < 4; ++nt)
#pragma unroll
        for (int rr = 0; rr < 4; ++rr) acc[mt][nt][rr] += biasv[nt];

    if (joiner) {
      if (c == 3 && w == 3 && l15 == 15) {
#pragma unroll
        for (int mt = 0; mt < 4; ++mt)
#pragma unroll
          for (int rr = 0; rr < 4; ++rr)
            s_blank[mt * 16 + l4 * 4 + rr] = acc[mt][3][rr];
      }
#pragma unroll
      for (int mt = 0; mt < 4; ++mt)
#pragma unroll
        for (int rr = 0; rr < 4; ++rr) {
          int row = mt * 16 + l4 * 4 + rr;
          int tg = s_tgt[row];
          if ((tg >> 8) == c && ((tg >> 6) & 3) == w && (tg & 15) == l15) {
            int ntv = (tg >> 4) & 3;
            float v01 = (ntv & 1) ? acc[mt][1][rr] : acc[mt][0][rr];
            float v23 = (ntv & 1) ? acc[mt][3][rr] : acc[mt][2][rr];
            s_label[row] = (ntv & 2) ? v23 : v01;
          }
        }
    } else {
      if (c == 3 && w == 3 && l15 == 15) {
#pragma unroll
        for (int mt = 0; mt < 4; ++mt)
#pragma unroll
          for (int rr = 0; rr < 4; ++rr)
            s_blank[mt * 16 + l4 * 4 + rr] = acc[mt][3][rr];
      }
#pragma unroll 1
      for (int u = 0; u < 64; ++u) {
        int tgu = s_tgt[u];
        if ((tgu >> 8) == c && ((tgu >> 6) & 3) == w) {
          int ntv = (tgu >> 4) & 3;
          if ((tgu & 15) == l15) {
#pragma unroll
            for (int mt = 0; mt < 4; ++mt)
#pragma unroll
              for (int rr = 0; rr < 4; ++rr) {
                float v01 = (ntv & 1) ? acc[mt][1][rr] : acc[mt][0][rr];
                float v23 = (ntv & 1) ? acc[mt][3][rr] : acc[mt][2][rr];
                float v = (ntv & 2) ? v23 : v01;
                ctc_lab[(g0 + mt * 16 + l4 * 4 + rr) * 64 + u] = v;
              }
          }
        }
      }
    }
#pragma unroll
    for (int mt = 0; mt < 4; ++mt)
#pragma unroll
      for (int rr = 0; rr < 4; ++rr)
        ssum[mt * 4 + rr] += __expf(acc[mt][0][rr]) + __expf(acc[mt][1][rr]) +
                             __expf(acc[mt][2][rr]) + __expf(acc[mt][3][rr]);
  }

#pragma unroll
  for (int ms = 1; ms < 16; ms <<= 1)
#pragma unroll
    for (int j = 0; j < 16; ++j) ssum[j] += __shfl_xor(ssum[j], ms, 64);
  if (l15 == 0) {
#pragma unroll
    for (int j = 0; j < 16; ++j)
      s_psum[w][(j >> 2) * 16 + l4 * 4 + (j & 3)] = ssum[j];
  }
  __syncthreads();

  if (tid < 64) {
    float tot = s_psum[0][tid] + s_psum[1][tid] + s_psum[2][tid] + s_psum[3][tid];
    float lse = __logf(tot);
    if (joiner) {
      int r = r0 + tid;
      int t = r / 65;
      int u = r - t * 65;
      lp_blank[(b * Tn + t) * UP1 + u] = s_blank[tid] - lse;
      if (u < Un) lp_label[(b * Tn + t) * Un + u] = s_label[tid] - lse;
    } else {
      ctc_blank[g0 + tid] = s_blank[tid] - lse;
      ctc_lse[g0 + tid] = lse;
    }
  }
}

// ---------------------------------------------------------------------------
// K3 k_dp: blocks 0-3 RNNT anti-diagonal DP; blocks 4-7 CTC DP.
// Per unroll-8 block: explicit LOAD PHASE (32 LDS reads into static-indexed
// register arrays) then COMPUTE PHASE (8 chain steps, memory-free) -> LDS
// latency batched once per 8 steps instead of exposed per step. Branch-free
// merges; sA stride 66 (conflict-free).
// ---------------------------------------------------------------------------
__global__ __launch_bounds__(256) void k_dp(
    const float* __restrict__ lp_blank, const float* __restrict__ lp_label,
    const float* __restrict__ ctc_blank, const float* __restrict__ ctc_lse,
    const float* __restrict__ ctc_lab,
    const int* __restrict__ target,
    const int* __restrict__ flen, const int* __restrict__ tlen,
    float* __restrict__ out) {
  __shared__ float sA[256 * 66];             // RNNT lp_blank[t][u], stride 66
  __shared__ __align__(16) float sB[16384];  // RNNT lp_label / CTC raw labels
  __shared__ float sC[256], sD[256];         // CTC blank / lse
  __shared__ float cT[129];
  const int tid = threadIdx.x;
  const int l = tid & 63;

  if (blockIdx.x < 4) {
    const int b = blockIdx.x;
    for (int i = tid; i < 16640; i += 256) {
      int r = i / 65, cidx = i - r * 65;
      sA[r * 66 + cidx] = lp_blank[b * 16640 + i];
    }
    {
      const f32x4* g2 = (const f32x4*)(lp_label + b * 16384);
      f32x4* s2 = (f32x4*)sB;
      for (int i = tid; i < 4096; i += 256) s2[i] = g2[i];
    }
    __syncthreads();
    if (tid < 64) {
      const int ft = flen[b], tl = tlen[b];
      const int dstar = ft - 1 + tl;
      const int lc = (l >= 1) ? l - 1 : 0;
      float a = (l == 0) ? 0.0f : NEGF;
      float a64 = NEGF, cap = NEGF;
      for (int d0 = 1; d0 <= 313; d0 += 8) {  // d up to 320 >= 319; pad neutral
        float vb[8], vl[8], vb64[8], vl64[8];
#pragma unroll
        for (int j = 0; j < 8; ++j) {  // LOAD PHASE (no dep on chain)
          const int d = d0 + j;
          const int t = d - l;
          const int tbc = (t < 1) ? 1 : (t > 255 ? 255 : t);
          const int tcc = (t < 0) ? 0 : (t > 255 ? 255 : t);
          vb[j] = sA[(tbc - 1) * 66 + l];
          vl[j] = sB[tcc * 64 + lc];
          const int t64 = d - 64;
          const int t64b = (t64 < 1) ? 1 : (t64 > 255 ? 255 : t64);
          const int t64c = (t64 < 0) ? 0 : (t64 > 255 ? 255 : t64);
          vb64[j] = sA[(t64b - 1) * 66 + 64];
          vl64[j] = sB[t64c * 64 + 63];
        }
#pragma unroll
        for (int j = 0; j < 8; ++j) {  // COMPUTE PHASE (memory-free)
          const int d = d0 + j;
          const int t = d - l;
          const int t64 = d - 64;
          float aleft = shfl_up1(a);
          bool valid = (t >= 0) && (t < Tn);
          float up = (valid && (t >= 1)) ? (a + vb[j]) : NEGF;
          float lft = (valid && (l >= 1)) ? (aleft + vl[j]) : NEGF;
          float nw = valid ? laddexp(up, lft) : NEGF;
          float up64 = (t64 >= 1) ? (a64 + vb64[j]) : NEGF;
          float nw64 = laddexp(up64, a + vl64[j]);
          bool s64 = (l == 63) && (t64 >= 0) && (t64 < Tn);
          a = nw;
          a64 = s64 ? nw64 : a64;
          bool hit = (d == dstar);
          cap = (hit && (l == tl)) ? a : cap;
          cap = (hit && (tl == 64) && (l == 63)) ? a64 : cap;
        }
      }
      bool owner = (tl < 64) ? (l == tl) : (l == 63);
      if (owner) atomicAdd(out, -0.25f * (cap + sA[(ft - 1) * 66 + tl]));
    }
  } else {
    const int b = blockIdx.x - 4;
    {
      const f32x4* g2 = (const f32x4*)(ctc_lab + b * 16384);
      f32x4* s2 = (f32x4*)sB;
      for (int i = tid; i < 4096; i += 256) s2[i] = g2[i];
      sC[tid] = ctc_blank[b * 256 + tid];
      sD[tid] = ctc_lse[b * 256 + tid];
    }
    __syncthreads();
    if (tid < 64) {
      const int ft = flen[b], tl = tlen[b];
      const int tg = target[b * Un + l];
      const int tgp = (l >= 1) ? target[b * Un + l - 1] : -1;
      const bool skip1 = (l >= 1) && (tg != tgp);
      float a0 = (l == 0) ? sC[0] : NEGF;
      float a1 = (l == 0) ? (sB[0] - sD[0]) : NEGF;
      float a2 = NEGF;
      for (int t0 = 1; t0 <= 249; t0 += 8) {  // t up to 256; pad frozen
        float ebv[8], e1v[8];
#pragma unroll
        for (int j = 0; j < 8; ++j) {  // LOAD PHASE
          const int tc = (t0 + j > 255) ? 255 : t0 + j;
          ebv[j] = sC[tc];
          e1v[j] = sB[tc * 64 + l] - sD[tc];
        }
#pragma unroll
        for (int j = 0; j < 8; ++j) {  // COMPUTE PHASE
          const int t = t0 + j;
          float pm1 = shfl_up1(a1);
          pm1 = (l == 0) ? NEGF : pm1;
          float n0 = ebv[j] + laddexp(a0, pm1);
          float n1 = e1v[j] + laddexp3(a1, a0, skip1 ? pm1 : NEGF);
          float n2 = ebv[j] + laddexp(a2, a1);  // all lanes; lane 63 keeps
          bool run = (t < ft);
          a0 = run ? n0 : a0;
          a1 = run ? n1 : a1;
          a2 = (run && (l == 63)) ? n2 : a2;
        }
      }
      cT[2 * l] = a0;
      cT[2 * l + 1] = a1;
      if (l == 63) cT[128] = a2;
      __builtin_amdgcn_s_waitcnt(0);  // intra-wave lgkm drain before readback
      if (l == 0) {
        int sl = 2 * tl;
        float ll = laddexp(cT[sl], cT[sl - 1]);
        float lb = (ll < NEGF * 0.5f) ? 0.0f : -ll;
        atomicAdd(out, CTCW * 0.25f * lb);
      }
    }
  }
}

// ---------------------------------------------------------------------------
extern "C" void kernel_launch(void* const* d_in, const int* in_sizes, int n_in,
                              void* d_out, int out_size, void* d_ws, size_t ws_size,
                              hipStream_t stream) {
  (void)in_sizes; (void)n_in; (void)out_size; (void)ws_size;
  const float* x_enc = (const float*)d_in[0];
  const float* x_dec = (const float*)d_in[1];
  const float* W_enc = (const float*)d_in[2];
  const float* b_enc = (const float*)d_in[3];
  const float* W_dec = (const float*)d_in[4];
  const float* b_dec = (const float*)d_in[5];
  const float* W_out = (const float*)d_in[6];
  const float* b_out = (const float*)d_in[7];
  const float* W_ctc = (const float*)d_in[8];
  const float* b_ctc = (const float*)d_in[9];
  const int* target = (const int*)d_in[10];
  const int* flen = (const int*)d_in[11];
  const int* tlen = (const int*)d_in[12];

  float* ws = (float*)d_ws;
  float* enc_lin = ws;                    // 262144
  float* dec_lin = ws + 262144;           // 66560
  float* lp_blank = ws + 328704;          // 66560
  float* lp_label = ws + 395264;          // 65536
  float* ctc_blank = ws + 460800;         // 1024
  float* ctc_lse = ws + 461824;           // 1024
  float* ctc_lab = ws + 462848;           // 65536
  unsigned short* Wt_out = (unsigned short*)(ws + 528384);  // 262144 bf16 (tiled)
  unsigned short* Wt_ctc = Wt_out + 262144;                 // 262144 bf16 (tiled)
  // Wt_enc/Wt_dec alias lp_blank/lp_label (disjoint lifetimes).
  unsigned short* Wt_enc = (unsigned short*)lp_blank;       // 65536 bf16
  unsigned short* Wt_dec = (unsigned short*)lp_label;       // 65536 bf16
  float* out = (float*)d_out;

  k_prep<<<dim3(160), dim3(256), 0, stream>>>(
      W_enc, W_dec, W_out, W_ctc, Wt_enc, Wt_dec, Wt_out, Wt_ctc, out);
  k_lin<<<dim3(21), dim3(256), 0, stream>>>(
      x_enc, x_dec, Wt_enc, b_enc, Wt_dec, b_dec, enc_lin, dec_lin);
  k_join2<<<dim3(1056), dim3(256), 0, stream>>>(
      enc_lin, dec_lin, Wt_out, b_out, x_enc, Wt_ctc, b_ctc, target,
      lp_blank, lp_label, ctc_blank, ctc_lse, ctc_lab);
  k_dp<<<dim3(8), dim3(64 * 4), 0, stream>>>(
      lp_blank, lp_label, ctc_blank, ctc_lse, ctc_lab, target, flen, tlen, out);
}

// Round 8
// 169.125 us; speedup vs baseline: 1.2931x; 1.0298x over previous
//
#include <hip/hip_runtime.h>
#include <hip/hip_bf16.h>

#define Bn 4
#define Tn 256
#define Un 64
#define UP1 65
#define Vn 1024
#define Dn 256
#define Hn 256
#define BLANKC 1023
#define NEGF (-1.0e30f)
#define CTCW 0.3f

typedef __attribute__((ext_vector_type(8))) short short8;
typedef __attribute__((ext_vector_type(4))) float f32x4;
typedef __attribute__((ext_vector_type(4))) unsigned int u32x4;

#define GLD_LDS16(gp, lp)                                                      \
  __builtin_amdgcn_global_load_lds(                                            \
      (const __attribute__((address_space(1))) void*)(gp),                     \
      (__attribute__((address_space(3))) void*)(lp), 16, 0, 0)

static __device__ __forceinline__ unsigned short f2bf(float f) {
  unsigned int u = __float_as_uint(f);
  u += 0x7FFFu + ((u >> 16) & 1u);
  return (unsigned short)(u >> 16);
}
static __device__ __forceinline__ unsigned int pack2bf(float a, float b) {
  return (unsigned int)f2bf(a) | ((unsigned int)f2bf(b) << 16);
}
static __device__ __forceinline__ float ftanh(float x) {
  float e = __expf(2.0f * x);
  return 1.0f - 2.0f / (e + 1.0f);
}
static __device__ __forceinline__ float laddexp(float a, float b) {
  float m = fmaxf(a, b), n = fminf(a, b);
  return m + __logf(1.0f + __expf(n - m));
}
static __device__ __forceinline__ float laddexp3(float a, float b, float c) {
  float m = fmaxf(fmaxf(a, b), c);
  return m + __logf(__expf(a - m) + __expf(b - m) + __expf(c - m));
}
// lane i <- lane i-1 (lane 0 gets 0; callers override lane 0). DPP wave_shr:1.
static __device__ __forceinline__ float shfl_up1(float x) {
  int r = __builtin_amdgcn_update_dpp(0, __float_as_int(x), 0x138, 0xF, 0xF, false);
  return __int_as_float(r);
}

// ---------------------------------------------------------------------------
// K1 k_prep: W_out/W_ctc -> step-tiled bf16 layout Wt2[(c,ks)][sub][col][8k];
// W_enc/W_dec -> flat bf16 transpose. Zeroes d_out.
// ---------------------------------------------------------------------------
__global__ __launch_bounds__(256) void k_prep(
    const float* __restrict__ W_enc, const float* __restrict__ W_dec,
    const float* __restrict__ W_out, const float* __restrict__ W_ctc,
    unsigned short* __restrict__ Wt_enc, unsigned short* __restrict__ Wt_dec,
    unsigned short* __restrict__ Wt_out, unsigned short* __restrict__ Wt_ctc,
    float* __restrict__ out) {
  const int blk = blockIdx.x, tid = threadIdx.x;
  if (blk == 0 && tid == 0) out[0] = 0.0f;
  __shared__ float tilebuf[64][65];
  if (blk < 128) {
    const float* Wsrc = (blk < 64) ? W_out : W_ctc;
    unsigned short* Wd = (blk < 64) ? Wt_out : Wt_ctc;
    const int tt = blk & 63;
    const int k0 = (tt & 3) * 64, v0 = (tt >> 2) * 64;
#pragma unroll
    for (int rep = 0; rep < 16; ++rep) {
      int e = rep * 256 + tid;
      int rr = e >> 6, cc = e & 63;  // rr: k-off, cc: n-off
      tilebuf[rr][cc] = Wsrc[(k0 + rr) * 1024 + (v0 + cc)];
    }
    __syncthreads();
#pragma unroll
    for (int rep = 0; rep < 16; ++rep) {
      int e = rep * 256 + tid;
      int nn = e >> 6, kk = e & 63;
      int n = v0 + nn, k = k0 + kk;
      int c = n >> 8, col = n & 255;
      int ks = k >> 5, sub = (k >> 3) & 3, k7 = k & 7;
      Wd[(c * 8 + ks) * 8192 + sub * 2048 + col * 8 + k7] = f2bf(tilebuf[kk][nn]);
    }
  } else {
    const float* Wsrc = (blk < 144) ? W_enc : W_dec;
    unsigned short* Wd = (blk < 144) ? Wt_enc : Wt_dec;
    const int tt = (blk - 128) & 15;
    const int k0 = (tt & 3) * 64, v0 = (tt >> 2) * 64;
#pragma unroll
    for (int rep = 0; rep < 16; ++rep) {
      int e = rep * 256 + tid;
      int rr = e >> 6, cc = e & 63;
      tilebuf[rr][cc] = Wsrc[(k0 + rr) * 256 + (v0 + cc)];
    }
    __syncthreads();
#pragma unroll
    for (int rep = 0; rep < 16; ++rep) {
      int e = rep * 256 + tid;
      int rr = e >> 6, cc = e & 63;
      Wd[(v0 + rr) * 256 + (k0 + cc)] = f2bf(tilebuf[cc][rr]);
    }
  }
}

// ---------------------------------------------------------------------------
// K1b k_lin: enc_lin / dec_lin via MFMA (tiny).
// ---------------------------------------------------------------------------
__global__ __launch_bounds__(256) void k_lin(
    const float* __restrict__ x_enc, const float* __restrict__ x_dec,
    const unsigned short* __restrict__ Wt_enc, const float* __restrict__ b_enc,
    const unsigned short* __restrict__ Wt_dec, const float* __restrict__ b_dec,
    float* __restrict__ enc_lin, float* __restrict__ dec_lin) {
  __shared__ __align__(16) char Asw[64 * 512];
  const int tid = threadIdx.x;
  const int w = tid >> 6, l = tid & 63;
  const int l15 = l & 15, l4 = l >> 4;
  const bool enc = blockIdx.x < 16;
  const int m0 = enc ? blockIdx.x * 64 : (blockIdx.x - 16) * 64;
  const int Mlim = enc ? 1024 : 260;
  const float* xp = enc ? x_enc : x_dec;
  const unsigned short* Wt = enc ? Wt_enc : Wt_dec;
  const float* bias = enc ? b_enc : b_dec;
  float* outp = enc ? enc_lin : dec_lin;

#pragma unroll
  for (int it = 0; it < 8; ++it) {
    int e = (it << 8) + tid;
    int i = e >> 5;
    int k0 = (e & 31) << 3;
    int r = m0 + i;
    if (r > Mlim - 1) r = Mlim - 1;
    const float* sp = xp + r * 256 + k0;
    f32x4 e0 = *(const f32x4*)sp;
    f32x4 e1 = *(const f32x4*)(sp + 4);
    u32x4 pv;
    pv[0] = pack2bf(e0[0], e0[1]);
    pv[1] = pack2bf(e0[2], e0[3]);
    pv[2] = pack2bf(e1[0], e1[1]);
    pv[3] = pack2bf(e1[2], e1[3]);
    int byt = (i << 9) + (k0 << 1);
    byt ^= (i & 7) << 4;
    *(u32x4*)(Asw + byt) = pv;
  }
  __syncthreads();

  const int nb = w * 64;
  f32x4 acc[4][4] = {};
#pragma unroll
  for (int ks = 0; ks < 8; ++ks) {
    int k = ks * 32 + l4 * 8;
    short8 af[4];
#pragma unroll
    for (int mt = 0; mt < 4; ++mt) {
      int i = mt * 16 + l15;
      int byt = (i << 9) + (k << 1);
      byt ^= (i & 7) << 4;
      af[mt] = *(const short8*)(Asw + byt);
    }
    short8 bfr[4];
#pragma unroll
    for (int nt = 0; nt < 4; ++nt) {
      int n = nb + nt * 16 + l15;
      bfr[nt] = *(const short8*)(Wt + n * 256 + k);
    }
#pragma unroll
    for (int mt = 0; mt < 4; ++mt)
#pragma unroll
      for (int nt = 0; nt < 4; ++nt)
        acc[mt][nt] = __builtin_amdgcn_mfma_f32_16x16x32_bf16(
            af[mt], bfr[nt], acc[mt][nt], 0, 0, 0);
  }
  float biasv[4];
#pragma unroll
  for (int nt = 0; nt < 4; ++nt) biasv[nt] = bias[nb + nt * 16 + l15];
#pragma unroll
  for (int mt = 0; mt < 4; ++mt)
#pragma unroll
    for (int rr = 0; rr < 4; ++rr) {
      int row = m0 + mt * 16 + l4 * 4 + rr;
      if (row < Mlim) {
#pragma unroll
        for (int nt = 0; nt < 4; ++nt)
          outp[row * 256 + nb + nt * 16 + l15] = acc[mt][nt][rr] + biasv[nt];
      }
    }
}

// ---------------------------------------------------------------------------
// K2 merged: blocks 0-15 = CTC head; blocks 16-1055 = joiner.
// Counted-vmcnt double-buffer (m201 pattern): per step s,
//   stage(s+1) -> s_waitcnt vmcnt(4) -> s_barrier -> ds_read+MFMA -> s_barrier
// vmcnt never drained to 0 in the joiner main loop. CTC epilogue stores are
// followed by vmcnt(0) so the hand count stays valid for those blocks.
// ---------------------------------------------------------------------------
__global__ __launch_bounds__(256, 2) void k_join2(
    const float* __restrict__ enc_lin, const float* __restrict__ dec_lin,
    const unsigned short* __restrict__ Wt_out, const float* __restrict__ b_out,
    const float* __restrict__ x_enc,
    const unsigned short* __restrict__ Wt_ctc, const float* __restrict__ b_ctc,
    const int* __restrict__ target,
    float* __restrict__ lp_blank, float* __restrict__ lp_label,
    float* __restrict__ ctc_blank, float* __restrict__ ctc_lse,
    float* __restrict__ ctc_lab) {
  __shared__ __align__(16) char Asw[64 * 512];    // 32KB A tile
  __shared__ __align__(16) char Bsw[2 * 16384];   // 2 x 16KB B step buffers
  __shared__ float s_psum[4][64];
  __shared__ float s_blank[64], s_label[64];
  __shared__ int s_tgt[64];

  const int tid = threadIdx.x;
  const int w = tid >> 6, l = tid & 63;
  const int l15 = l & 15, l4 = l >> 4;

  const bool joiner = blockIdx.x >= 16;
  const unsigned short* Wt = joiner ? Wt_out : Wt_ctc;
  const float* bias = joiner ? b_out : b_ctc;

  // step s (=c*8+ks) is the linear 16KB chunk Wt2 + s*8192 elems.
  auto stageB = [&](int s, int buf) {
    const unsigned short* base = Wt + s * 8192 + tid * 8;
#pragma unroll
    for (int r = 0; r < 4; ++r)
      GLD_LDS16(base + r * 2048, Bsw + buf * 16384 + r * 4096 + (w << 10));
  };

  int b, r0 = 0, g0 = 0;
  if (joiner) {
    const int bid = blockIdx.x - 16;
    b = bid / 260;
    r0 = (bid % 260) * 64;
#pragma unroll
    for (int it = 0; it < 8; ++it) {
      int e = (it << 8) + tid;
      int i = e >> 5;
      int k0 = (e & 31) << 3;
      int r = r0 + i;
      int t = r / 65;
      int u = r - t * 65;
      const float* ep = enc_lin + ((b * Tn + t) * Hn + k0);
      const float* dp = dec_lin + ((b * UP1 + u) * Hn + k0);
      f32x4 e0 = *(const f32x4*)ep;
      f32x4 e1 = *(const f32x4*)(ep + 4);
      f32x4 d0 = *(const f32x4*)dp;
      f32x4 d1 = *(const f32x4*)(dp + 4);
      u32x4 pv;
      pv[0] = pack2bf(ftanh(e0[0] + d0[0]), ftanh(e0[1] + d0[1]));
      pv[1] = pack2bf(ftanh(e0[2] + d0[2]), ftanh(e0[3] + d0[3]));
      pv[2] = pack2bf(ftanh(e1[0] + d1[0]), ftanh(e1[1] + d1[1]));
      pv[3] = pack2bf(ftanh(e1[2] + d1[2]), ftanh(e1[3] + d1[3]));
      int byt = (i << 9) + (k0 << 1);
      byt ^= (i & 7) << 4;
      *(u32x4*)(Asw + byt) = pv;
    }
    if (tid < 64) {
      int u = (r0 + tid) % 65;
      s_tgt[tid] = (u < Un) ? target[b * Un + u] : -1;
    }
  } else {
    g0 = blockIdx.x * 64;
    b = g0 >> 8;
#pragma unroll
    for (int it = 0; it < 8; ++it) {
      int e = (it << 8) + tid;
      int i = e >> 5;
      int k0 = (e & 31) << 3;
      const float* sp = x_enc + (g0 + i) * Dn + k0;
      f32x4 e0 = *(const f32x4*)sp;
      f32x4 e1 = *(const f32x4*)(sp + 4);
      u32x4 pv;
      pv[0] = pack2bf(e0[0], e0[1]);
      pv[1] = pack2bf(e0[2], e0[3]);
      pv[2] = pack2bf(e1[0], e1[1]);
      pv[3] = pack2bf(e1[2], e1[3]);
      int byt = (i << 9) + (k0 << 1);
      byt ^= (i & 7) << 4;
      *(u32x4*)(Asw + byt) = pv;
    }
    if (tid < 64) s_tgt[tid] = target[b * Un + tid];
  }
  stageB(0, 0);
  // Drain prologue (stage 0 + A ds_writes), once.
  asm volatile("s_waitcnt vmcnt(0) lgkmcnt(0)" ::: "memory");
  __builtin_amdgcn_s_barrier();

  float ssum[16];
#pragma unroll
  for (int j = 0; j < 16; ++j) ssum[j] = 0.0f;

#pragma unroll 1
  for (int c = 0; c < 4; ++c) {
    f32x4 acc[4][4] = {};
#pragma unroll
    for (int ks = 0; ks < 8; ++ks) {
      const int s = c * 8 + ks;
      if (ks != 7 || c < 3) {
        stageB(s + 1, (s + 1) & 1);
        asm volatile("s_waitcnt vmcnt(4)" ::: "memory");  // stage(s) done
      } else {
        asm volatile("s_waitcnt vmcnt(0)" ::: "memory");  // last step
      }
      __builtin_amdgcn_s_barrier();  // buf[s&1] visible to all waves
      __builtin_amdgcn_sched_barrier(0);
      const int k = ks * 32 + l4 * 8;
      short8 af[4];
#pragma unroll
      for (int mt = 0; mt < 4; ++mt) {
        int i = mt * 16 + l15;
        int byt = (i << 9) + (k << 1);
        byt ^= (i & 7) << 4;
        af[mt] = *(const short8*)(Asw + byt);
      }
      short8 bfr[4];
#pragma unroll
      for (int nt = 0; nt < 4; ++nt) {
        int byt = (ks & 1) * 16384 + l4 * 4096 + (w * 64 + nt * 16 + l15) * 16;
        bfr[nt] = *(const short8*)(Bsw + byt);
      }
#pragma unroll
      for (int mt = 0; mt < 4; ++mt)
#pragma unroll
        for (int nt = 0; nt < 4; ++nt)
          acc[mt][nt] = __builtin_amdgcn_mfma_f32_16x16x32_bf16(
              af[mt], bfr[nt], acc[mt][nt], 0, 0, 0);
      __builtin_amdgcn_sched_barrier(0);
      __builtin_amdgcn_s_barrier();  // all waves consumed buf[s&1]
    }
    const int nb = c * 256 + w * 64;
    float biasv[4];
#pragma unroll
    for (int nt = 0; nt < 4; ++nt) biasv[nt] = bias[nb + nt * 16 + l15];
#pragma unroll
    for (int mt = 0; mt < 4; ++mt)
#pragma unroll
      for (int nt = 0; nt < 4; ++nt)
#pragma unroll
        for (int rr = 0; rr < 4; ++rr) acc[mt][nt][rr] += biasv[nt];

    if (joiner) {
      if (c == 3 && w == 3 && l15 == 15) {
#pragma unroll
        for (int mt = 0; mt < 4; ++mt)
#pragma unroll
          for (int rr = 0; rr < 4; ++rr)
            s_blank[mt * 16 + l4 * 4 + rr] = acc[mt][3][rr];
      }
#pragma unroll
      for (int mt = 0; mt < 4; ++mt)
#pragma unroll
        for (int rr = 0; rr < 4; ++rr) {
          int row = mt * 16 + l4 * 4 + rr;
          int tg = s_tgt[row];
          if ((tg >> 8) == c && ((tg >> 6) & 3) == w && (tg & 15) == l15) {
            int ntv = (tg >> 4) & 3;
            float v01 = (ntv & 1) ? acc[mt][1][rr] : acc[mt][0][rr];
            float v23 = (ntv & 1) ? acc[mt][3][rr] : acc[mt][2][rr];
            s_label[row] = (ntv & 2) ? v23 : v01;
          }
        }
    } else {
      if (c == 3 && w == 3 && l15 == 15) {
#pragma unroll
        for (int mt = 0; mt < 4; ++mt)
#pragma unroll
          for (int rr = 0; rr < 4; ++rr)
            s_blank[mt * 16 + l4 * 4 + rr] = acc[mt][3][rr];
      }
#pragma unroll 1
      for (int u = 0; u < 64; ++u) {
        int tgu = s_tgt[u];
        if ((tgu >> 8) == c && ((tgu >> 6) & 3) == w) {
          int ntv = (tgu >> 4) & 3;
          if ((tgu & 15) == l15) {
#pragma unroll
            for (int mt = 0; mt < 4; ++mt)
#pragma unroll
              for (int rr = 0; rr < 4; ++rr) {
                float v01 = (ntv & 1) ? acc[mt][1][rr] : acc[mt][0][rr];
                float v23 = (ntv & 1) ? acc[mt][3][rr] : acc[mt][2][rr];
                float v = (ntv & 2) ? v23 : v01;
                ctc_lab[(g0 + mt * 16 + l4 * 4 + rr) * 64 + u] = v;
              }
          }
        }
      }
      // Drain the label stores so the staged-load vmcnt hand-count stays valid.
      asm volatile("s_waitcnt vmcnt(0)" ::: "memory");
    }
#pragma unroll
    for (int mt = 0; mt < 4; ++mt)
#pragma unroll
      for (int rr = 0; rr < 4; ++rr)
        ssum[mt * 4 + rr] += __expf(acc[mt][0][rr]) + __expf(acc[mt][1][rr]) +
                             __expf(acc[mt][2][rr]) + __expf(acc[mt][3][rr]);
  }

#pragma unroll
  for (int ms = 1; ms < 16; ms <<= 1)
#pragma unroll
    for (int j = 0; j < 16; ++j) ssum[j] += __shfl_xor(ssum[j], ms, 64);
  if (l15 == 0) {
#pragma unroll
    for (int j = 0; j < 16; ++j)
      s_psum[w][(j >> 2) * 16 + l4 * 4 + (j & 3)] = ssum[j];
  }
  __syncthreads();

  if (tid < 64) {
    float tot = s_psum[0][tid] + s_psum[1][tid] + s_psum[2][tid] + s_psum[3][tid];
    float lse = __logf(tot);
    if (joiner) {
      int r = r0 + tid;
      int t = r / 65;
      int u = r - t * 65;
      lp_blank[(b * Tn + t) * UP1 + u] = s_blank[tid] - lse;
      if (u < Un) lp_label[(b * Tn + t) * Un + u] = s_label[tid] - lse;
    } else {
      ctc_blank[g0 + tid] = s_blank[tid] - lse;
      ctc_lse[g0 + tid] = lse;
    }
  }
}

// ---------------------------------------------------------------------------
// K3 k_dp: blocks 0-3 RNNT anti-diagonal DP; blocks 4-7 CTC DP.
// Next-block register prefetch: while computing 8 chain steps from the
// CURRENT register set, the NEXT 8 steps' LDS reads are already issued —
// pinned with sched_barrier(0) so the scheduler cannot re-interleave them
// into the serial laddexp chain (the R5-R7 stall).
// ---------------------------------------------------------------------------
__global__ __launch_bounds__(256) void k_dp(
    const float* __restrict__ lp_blank, const float* __restrict__ lp_label,
    const float* __restrict__ ctc_blank, const float* __restrict__ ctc_lse,
    const float* __restrict__ ctc_lab,
    const int* __restrict__ target,
    const int* __restrict__ flen, const int* __restrict__ tlen,
    float* __restrict__ out) {
  __shared__ float sA[256 * 66];             // RNNT lp_blank[t][u], stride 66
  __shared__ __align__(16) float sB[16384];  // RNNT lp_label / CTC raw labels
  __shared__ float sC[256], sD[256];         // CTC blank / lse
  __shared__ float cT[129];
  const int tid = threadIdx.x;
  const int l = tid & 63;

  if (blockIdx.x < 4) {
    const int b = blockIdx.x;
    for (int i = tid; i < 16640; i += 256) {
      int r = i / 65, cidx = i - r * 65;
      sA[r * 66 + cidx] = lp_blank[b * 16640 + i];
    }
    {
      const f32x4* g2 = (const f32x4*)(lp_label + b * 16384);
      f32x4* s2 = (f32x4*)sB;
      for (int i = tid; i < 4096; i += 256) s2[i] = g2[i];
    }
    __syncthreads();
    if (tid < 64) {
      const int ft = flen[b], tl = tlen[b];
      const int dstar = ft - 1 + tl;
      const int lc = (l >= 1) ? l - 1 : 0;

#define RLOAD(D0, VB, VL, VB64, VL64)                                          \
  _Pragma("unroll") for (int j = 0; j < 8; ++j) {                              \
    const int d_ = (D0) + j;                                                   \
    const int t_ = d_ - l;                                                     \
    const int tbc_ = (t_ < 1) ? 1 : (t_ > 255 ? 255 : t_);                     \
    const int tcc_ = (t_ < 0) ? 0 : (t_ > 255 ? 255 : t_);                     \
    VB[j] = sA[(tbc_ - 1) * 66 + l];                                           \
    VL[j] = sB[tcc_ * 64 + lc];                                                \
    const int t64_ = d_ - 64;                                                  \
    const int t64b_ = (t64_ < 1) ? 1 : (t64_ > 255 ? 255 : t64_);              \
    const int t64c_ = (t64_ < 0) ? 0 : (t64_ > 255 ? 255 : t64_);              \
    VB64[j] = sA[(t64b_ - 1) * 66 + 64];                                       \
    VL64[j] = sB[t64c_ * 64 + 63];                                             \
  }

      float cvb[8], cvl[8], cvb64[8], cvl64[8];
      RLOAD(1, cvb, cvl, cvb64, cvl64);
      float a = (l == 0) ? 0.0f : NEGF;
      float a64 = NEGF, cap = NEGF;
      for (int d0 = 1; d0 <= 313; d0 += 8) {  // d up to 320 >= 319
        float nvb[8], nvl[8], nvb64[8], nvl64[8];
        RLOAD(d0 + 8, nvb, nvl, nvb64, nvl64);  // prefetch next block
        __builtin_amdgcn_sched_barrier(0);
#pragma unroll
        for (int j = 0; j < 8; ++j) {  // compute current block (memory-free)
          const int d = d0 + j;
          const int t = d - l;
          const int t64 = d - 64;
          float aleft = shfl_up1(a);
          bool valid = (t >= 0) && (t < Tn);
          float up = (valid && (t >= 1)) ? (a + cvb[j]) : NEGF;
          float lft = (valid && (l >= 1)) ? (aleft + cvl[j]) : NEGF;
          float nw = valid ? laddexp(up, lft) : NEGF;
          float up64 = (t64 >= 1) ? (a64 + cvb64[j]) : NEGF;
          float nw64 = laddexp(up64, a + cvl64[j]);
          bool s64 = (l == 63) && (t64 >= 0) && (t64 < Tn);
          a = nw;
          a64 = s64 ? nw64 : a64;
          bool hit = (d == dstar);
          cap = (hit && (l == tl)) ? a : cap;
          cap = (hit && (tl == 64) && (l == 63)) ? a64 : cap;
        }
        __builtin_amdgcn_sched_barrier(0);
#pragma unroll
        for (int j = 0; j < 8; ++j) {
          cvb[j] = nvb[j];
          cvl[j] = nvl[j];
          cvb64[j] = nvb64[j];
          cvl64[j] = nvl64[j];
        }
      }
#undef RLOAD
      bool owner = (tl < 64) ? (l == tl) : (l == 63);
      if (owner) atomicAdd(out, -0.25f * (cap + sA[(ft - 1) * 66 + tl]));
    }
  } else {
    const int b = blockIdx.x - 4;
    {
      const f32x4* g2 = (const f32x4*)(ctc_lab + b * 16384);
      f32x4* s2 = (f32x4*)sB;
      for (int i = tid; i < 4096; i += 256) s2[i] = g2[i];
      sC[tid] = ctc_blank[b * 256 + tid];
      sD[tid] = ctc_lse[b * 256 + tid];
    }
    __syncthreads();
    if (tid < 64) {
      const int ft = flen[b], tl = tlen[b];
      const int tg = target[b * Un + l];
      const int tgp = (l >= 1) ? target[b * Un + l - 1] : -1;
      const bool skip1 = (l >= 1) && (tg != tgp);

#define CLOAD(T0, EB, E1)                                                      \
  _Pragma("unroll") for (int j = 0; j < 8; ++j) {                              \
    const int tc_ = ((T0) + j > 255) ? 255 : (T0) + j;                         \
    EB[j] = sC[tc_];                                                           \
    E1[j] = sB[tc_ * 64 + l] - sD[tc_];                                        \
  }

      float ceb[8], ce1[8];
      CLOAD(1, ceb, ce1);
      float a0 = (l == 0) ? sC[0] : NEGF;
      float a1 = (l == 0) ? (sB[0] - sD[0]) : NEGF;
      float a2 = NEGF;
      for (int t0 = 1; t0 <= 249; t0 += 8) {  // t up to 256; pad frozen
        float neb[8], ne1[8];
        CLOAD(t0 + 8, neb, ne1);
        __builtin_amdgcn_sched_barrier(0);
#pragma unroll
        for (int j = 0; j < 8; ++j) {
          const int t = t0 + j;
          float pm1 = shfl_up1(a1);
          pm1 = (l == 0) ? NEGF : pm1;
          float n0 = ceb[j] + laddexp(a0, pm1);
          float n1 = ce1[j] + laddexp3(a1, a0, skip1 ? pm1 : NEGF);
          float n2 = ceb[j] + laddexp(a2, a1);
          bool run = (t < ft);
          a0 = run ? n0 : a0;
          a1 = run ? n1 : a1;
          a2 = (run && (l == 63)) ? n2 : a2;
        }
        __builtin_amdgcn_sched_barrier(0);
#pragma unroll
        for (int j = 0; j < 8; ++j) {
          ceb[j] = neb[j];
          ce1[j] = ne1[j];
        }
      }
#undef CLOAD
      cT[2 * l] = a0;
      cT[2 * l + 1] = a1;
      if (l == 63) cT[128] = a2;
      __builtin_amdgcn_s_waitcnt(0);  // intra-wave lgkm drain before readback
      if (l == 0) {
        int sl = 2 * tl;
        float ll = laddexp(cT[sl], cT[sl - 1]);
        float lb = (ll < NEGF * 0.5f) ? 0.0f : -ll;
        atomicAdd(out, CTCW * 0.25f * lb);
      }
    }
  }
}

// ---------------------------------------------------------------------------
extern "C" void kernel_launch(void* const* d_in, const int* in_sizes, int n_in,
                              void* d_out, int out_size, void* d_ws, size_t ws_size,
                              hipStream_t stream) {
  (void)in_sizes; (void)n_in; (void)out_size; (void)ws_size;
  const float* x_enc = (const float*)d_in[0];
  const float* x_dec = (const float*)d_in[1];
  const float* W_enc = (const float*)d_in[2];
  const float* b_enc = (const float*)d_in[3];
  const float* W_dec = (const float*)d_in[4];
  const float* b_dec = (const float*)d_in[5];
  const float* W_out = (const float*)d_in[6];
  const float* b_out = (const float*)d_in[7];
  const float* W_ctc = (const float*)d_in[8];
  const float* b_ctc = (const float*)d_in[9];
  const int* target = (const int*)d_in[10];
  const int* flen = (const int*)d_in[11];
  const int* tlen = (const int*)d_in[12];

  float* ws = (float*)d_ws;
  float* enc_lin = ws;                    // 262144
  float* dec_lin = ws + 262144;           // 66560
  float* lp_blank = ws + 328704;          // 66560
  float* lp_label = ws + 395264;          // 65536
  float* ctc_blank = ws + 460800;         // 1024
  float* ctc_lse = ws + 461824;           // 1024
  float* ctc_lab = ws + 462848;           // 65536
  unsigned short* Wt_out = (unsigned short*)(ws + 528384);  // 262144 bf16 (tiled)
  unsigned short* Wt_ctc = Wt_out + 262144;                 // 262144 bf16 (tiled)
  unsigned short* Wt_enc = (unsigned short*)lp_blank;       // 65536 bf16
  unsigned short* Wt_dec = (unsigned short*)lp_label;       // 65536 bf16
  float* out = (float*)d_out;

  k_prep<<<dim3(160), dim3(256), 0, stream>>>(
      W_enc, W_dec, W_out, W_ctc, Wt_enc, Wt_dec, Wt_out, Wt_ctc, out);
  k_lin<<<dim3(21), dim3(256), 0, stream>>>(
      x_enc, x_dec, Wt_enc, b_enc, Wt_dec, b_dec, enc_lin, dec_lin);
  k_join2<<<dim3(1056), dim3(256), 0, stream>>>(
      enc_lin, dec_lin, Wt_out, b_out, x_enc, Wt_ctc, b_ctc, target,
      lp_blank, lp_label, ctc_blank, ctc_lse, ctc_lab);
  k_dp<<<dim3(8), dim3(64 * 4), 0, stream>>>(
      lp_blank, lp_label, ctc_blank, ctc_lse, ctc_lab, target, flen, tlen, out);
}

// Round 9
// 149.838 us; speedup vs baseline: 1.4596x; 1.1287x over previous
//
#include <hip/hip_runtime.h>
#include <hip/hip_bf16.h>

#define Bn 4
#define Tn 256
#define Un 64
#define UP1 65
#define Vn 1024
#define Dn 256
#define Hn 256
#define BLANKC 1023
#define NEGF (-1.0e30f)
#define CTCW 0.3f

typedef __attribute__((ext_vector_type(8))) short short8;
typedef __attribute__((ext_vector_type(4))) float f32x4;
typedef __attribute__((ext_vector_type(4))) unsigned int u32x4;

static __device__ __forceinline__ unsigned short f2bf(float f) {
  unsigned int u = __float_as_uint(f);
  u += 0x7FFFu + ((u >> 16) & 1u);
  return (unsigned short)(u >> 16);
}
static __device__ __forceinline__ unsigned int pack2bf(float a, float b) {
  return (unsigned int)f2bf(a) | ((unsigned int)f2bf(b) << 16);
}
static __device__ __forceinline__ float ftanh(float x) {
  float e = __expf(2.0f * x);
  return 1.0f - 2.0f / (e + 1.0f);
}
static __device__ __forceinline__ float laddexp(float a, float b) {
  float m = fmaxf(a, b), n = fminf(a, b);
  return m + __logf(1.0f + __expf(n - m));
}
static __device__ __forceinline__ float laddexp3(float a, float b, float c) {
  float m = fmaxf(fmaxf(a, b), c);
  return m + __logf(__expf(a - m) + __expf(b - m) + __expf(c - m));
}
// lane i <- lane i-1 (lane 0 gets 0; callers mask lane 0). DPP wave_shr:1.
static __device__ __forceinline__ float shfl_up1(float x) {
  int r = __builtin_amdgcn_update_dpp(0, __float_as_int(x), 0x138, 0xF, 0xF, false);
  return __int_as_float(r);
}

// ---------------------------------------------------------------------------
// K1 k_prep: W_out/W_ctc -> step-tiled bf16 layout Wt2[s=(c,ks)][sub][col][8k];
// W_enc/W_dec -> flat bf16 transpose. Zeroes d_out.
// ---------------------------------------------------------------------------
__global__ __launch_bounds__(256) void k_prep(
    const float* __restrict__ W_enc, const float* __restrict__ W_dec,
    const float* __restrict__ W_out, const float* __restrict__ W_ctc,
    unsigned short* __restrict__ Wt_enc, unsigned short* __restrict__ Wt_dec,
    unsigned short* __restrict__ Wt_out, unsigned short* __restrict__ Wt_ctc,
    float* __restrict__ out) {
  const int blk = blockIdx.x, tid = threadIdx.x;
  if (blk == 0 && tid == 0) out[0] = 0.0f;
  __shared__ float tilebuf[64][65];
  if (blk < 128) {
    const float* Wsrc = (blk < 64) ? W_out : W_ctc;
    unsigned short* Wd = (blk < 64) ? Wt_out : Wt_ctc;
    const int tt = blk & 63;
    const int k0 = (tt & 3) * 64, v0 = (tt >> 2) * 64;
#pragma unroll
    for (int rep = 0; rep < 16; ++rep) {
      int e = rep * 256 + tid;
      int rr = e >> 6, cc = e & 63;  // rr: k-off, cc: n-off
      tilebuf[rr][cc] = Wsrc[(k0 + rr) * 1024 + (v0 + cc)];
    }
    __syncthreads();
#pragma unroll
    for (int rep = 0; rep < 16; ++rep) {
      int e = rep * 256 + tid;
      int nn = e >> 6, kk = e & 63;
      int n = v0 + nn, k = k0 + kk;
      int c = n >> 8, col = n & 255;
      int ks = k >> 5, sub = (k >> 3) & 3, k7 = k & 7;
      Wd[(c * 8 + ks) * 8192 + sub * 2048 + col * 8 + k7] = f2bf(tilebuf[kk][nn]);
    }
  } else {
    const float* Wsrc = (blk < 144) ? W_enc : W_dec;
    unsigned short* Wd = (blk < 144) ? Wt_enc : Wt_dec;
    const int tt = (blk - 128) & 15;
    const int k0 = (tt & 3) * 64, v0 = (tt >> 2) * 64;
#pragma unroll
    for (int rep = 0; rep < 16; ++rep) {
      int e = rep * 256 + tid;
      int rr = e >> 6, cc = e & 63;
      tilebuf[rr][cc] = Wsrc[(k0 + rr) * 256 + (v0 + cc)];
    }
    __syncthreads();
#pragma unroll
    for (int rep = 0; rep < 16; ++rep) {
      int e = rep * 256 + tid;
      int rr = e >> 6, cc = e & 63;
      Wd[(v0 + rr) * 256 + (k0 + cc)] = f2bf(tilebuf[cc][rr]);
    }
  }
}

// ---------------------------------------------------------------------------
// K1b k_lin: enc_lin / dec_lin via MFMA (tiny).
// ---------------------------------------------------------------------------
__global__ __launch_bounds__(256) void k_lin(
    const float* __restrict__ x_enc, const float* __restrict__ x_dec,
    const unsigned short* __restrict__ Wt_enc, const float* __restrict__ b_enc,
    const unsigned short* __restrict__ Wt_dec, const float* __restrict__ b_dec,
    float* __restrict__ enc_lin, float* __restrict__ dec_lin) {
  __shared__ __align__(16) char Asw[64 * 512];
  const int tid = threadIdx.x;
  const int w = tid >> 6, l = tid & 63;
  const int l15 = l & 15, l4 = l >> 4;
  const bool enc = blockIdx.x < 16;
  const int m0 = enc ? blockIdx.x * 64 : (blockIdx.x - 16) * 64;
  const int Mlim = enc ? 1024 : 260;
  const float* xp = enc ? x_enc : x_dec;
  const unsigned short* Wt = enc ? Wt_enc : Wt_dec;
  const float* bias = enc ? b_enc : b_dec;
  float* outp = enc ? enc_lin : dec_lin;

#pragma unroll
  for (int it = 0; it < 8; ++it) {
    int e = (it << 8) + tid;
    int i = e >> 5;
    int k0 = (e & 31) << 3;
    int r = m0 + i;
    if (r > Mlim - 1) r = Mlim - 1;
    const float* sp = xp + r * 256 + k0;
    f32x4 e0 = *(const f32x4*)sp;
    f32x4 e1 = *(const f32x4*)(sp + 4);
    u32x4 pv;
    pv[0] = pack2bf(e0[0], e0[1]);
    pv[1] = pack2bf(e0[2], e0[3]);
    pv[2] = pack2bf(e1[0], e1[1]);
    pv[3] = pack2bf(e1[2], e1[3]);
    int byt = (i << 9) + (k0 << 1);
    byt ^= (i & 7) << 4;
    *(u32x4*)(Asw + byt) = pv;
  }
  __syncthreads();

  const int nb = w * 64;
  f32x4 acc[4][4] = {};
#pragma unroll
  for (int ks = 0; ks < 8; ++ks) {
    int k = ks * 32 + l4 * 8;
    short8 af[4];
#pragma unroll
    for (int mt = 0; mt < 4; ++mt) {
      int i = mt * 16 + l15;
      int byt = (i << 9) + (k << 1);
      byt ^= (i & 7) << 4;
      af[mt] = *(const short8*)(Asw + byt);
    }
    short8 bfr[4];
#pragma unroll
    for (int nt = 0; nt < 4; ++nt) {
      int n = nb + nt * 16 + l15;
      bfr[nt] = *(const short8*)(Wt + n * 256 + k);
    }
#pragma unroll
    for (int mt = 0; mt < 4; ++mt)
#pragma unroll
      for (int nt = 0; nt < 4; ++nt)
        acc[mt][nt] = __builtin_amdgcn_mfma_f32_16x16x32_bf16(
            af[mt], bfr[nt], acc[mt][nt], 0, 0, 0);
  }
  float biasv[4];
#pragma unroll
  for (int nt = 0; nt < 4; ++nt) biasv[nt] = bias[nb + nt * 16 + l15];
#pragma unroll
  for (int mt = 0; mt < 4; ++mt)
#pragma unroll
    for (int rr = 0; rr < 4; ++rr) {
      int row = m0 + mt * 16 + l4 * 4 + rr;
      if (row < Mlim) {
#pragma unroll
        for (int nt = 0; nt < 4; ++nt)
          outp[row * 256 + nb + nt * 16 + l15] = acc[mt][nt][rr] + biasv[nt];
      }
    }
}

// ---------------------------------------------------------------------------
// K2 merged: blocks 0-15 = CTC head; blocks 16-1055 = joiner.
// BARRIER-FREE K-loop: B fragments load directly from the step-tiled Wt2
// (coalesced b128, L2-hot) into registers, software-pipelined one step ahead
// (cur/nxt + sched_barrier(0) per step to cap in-flight loads). A stays in
// swizzled LDS (read-only after one syncthreads). No LDS B, no lockstep.
// ---------------------------------------------------------------------------
__global__ __launch_bounds__(256) void k_join2(
    const float* __restrict__ enc_lin, const float* __restrict__ dec_lin,
    const unsigned short* __restrict__ Wt_out, const float* __restrict__ b_out,
    const float* __restrict__ x_enc,
    const unsigned short* __restrict__ Wt_ctc, const float* __restrict__ b_ctc,
    const int* __restrict__ target,
    float* __restrict__ lp_blank, float* __restrict__ lp_label,
    float* __restrict__ ctc_blank, float* __restrict__ ctc_lse,
    float* __restrict__ ctc_lab) {
  __shared__ __align__(16) char Asw[64 * 512];    // 32KB A tile
  __shared__ float s_psum[4][64];
  __shared__ float s_blank[64], s_label[64];
  __shared__ int s_tgt[64];

  const int tid = threadIdx.x;
  const int w = tid >> 6, l = tid & 63;
  const int l15 = l & 15, l4 = l >> 4;

  const bool joiner = blockIdx.x >= 16;
  const unsigned short* Wt = joiner ? Wt_out : Wt_ctc;
  const float* bias = joiner ? b_out : b_ctc;

  // This thread's B address base: step s, col = w*64 + nt*16 + l15, sub = l4:
  // elem = s*8192 + l4*2048 + col*8 + k7.
  const unsigned short* tb = Wt + l4 * 2048 + (w * 64 + l15) * 8;

  short8 bcur[4], bnxt[4];
#pragma unroll
  for (int nt = 0; nt < 4; ++nt) bcur[nt] = *(const short8*)(tb + nt * 128);

  int b, r0 = 0, g0 = 0;
  if (joiner) {
    const int bid = blockIdx.x - 16;
    b = bid / 260;
    r0 = (bid % 260) * 64;
#pragma unroll
    for (int it = 0; it < 8; ++it) {
      int e = (it << 8) + tid;
      int i = e >> 5;
      int k0 = (e & 31) << 3;
      int r = r0 + i;
      int t = r / 65;
      int u = r - t * 65;
      const float* ep = enc_lin + ((b * Tn + t) * Hn + k0);
      const float* dp = dec_lin + ((b * UP1 + u) * Hn + k0);
      f32x4 e0 = *(const f32x4*)ep;
      f32x4 e1 = *(const f32x4*)(ep + 4);
      f32x4 d0 = *(const f32x4*)dp;
      f32x4 d1 = *(const f32x4*)(dp + 4);
      u32x4 pv;
      pv[0] = pack2bf(ftanh(e0[0] + d0[0]), ftanh(e0[1] + d0[1]));
      pv[1] = pack2bf(ftanh(e0[2] + d0[2]), ftanh(e0[3] + d0[3]));
      pv[2] = pack2bf(ftanh(e1[0] + d1[0]), ftanh(e1[1] + d1[1]));
      pv[3] = pack2bf(ftanh(e1[2] + d1[2]), ftanh(e1[3] + d1[3]));
      int byt = (i << 9) + (k0 << 1);
      byt ^= (i & 7) << 4;
      *(u32x4*)(Asw + byt) = pv;
    }
    if (tid < 64) {
      int u = (r0 + tid) % 65;
      s_tgt[tid] = (u < Un) ? target[b * Un + u] : -1;
    }
  } else {
    g0 = blockIdx.x * 64;
    b = g0 >> 8;
#pragma unroll
    for (int it = 0; it < 8; ++it) {
      int e = (it << 8) + tid;
      int i = e >> 5;
      int k0 = (e & 31) << 3;
      const float* sp = x_enc + (g0 + i) * Dn + k0;
      f32x4 e0 = *(const f32x4*)sp;
      f32x4 e1 = *(const f32x4*)(sp + 4);
      u32x4 pv;
      pv[0] = pack2bf(e0[0], e0[1]);
      pv[1] = pack2bf(e0[2], e0[3]);
      pv[2] = pack2bf(e1[0], e1[1]);
      pv[3] = pack2bf(e1[2], e1[3]);
      int byt = (i << 9) + (k0 << 1);
      byt ^= (i & 7) << 4;
      *(u32x4*)(Asw + byt) = pv;
    }
    if (tid < 64) s_tgt[tid] = target[b * Un + tid];
  }
  __syncthreads();  // A tile + s_tgt ready; the ONLY pre-epilogue barrier

  float ssum[16];
#pragma unroll
  for (int j = 0; j < 16; ++j) ssum[j] = 0.0f;

#pragma unroll 1
  for (int c = 0; c < 4; ++c) {
    f32x4 acc[4][4] = {};
#pragma unroll
    for (int ks = 0; ks < 8; ++ks) {
      const int s = c * 8 + ks;
      const int sn = (s < 31) ? s + 1 : 31;  // clamp; extra last-step reload unused
      const unsigned short* nb_ = tb + sn * 8192;
#pragma unroll
      for (int nt = 0; nt < 4; ++nt) bnxt[nt] = *(const short8*)(nb_ + nt * 128);
      const int k = ks * 32 + l4 * 8;
      short8 af[4];
#pragma unroll
      for (int mt = 0; mt < 4; ++mt) {
        int i = mt * 16 + l15;
        int byt = (i << 9) + (k << 1);
        byt ^= (i & 7) << 4;
        af[mt] = *(const short8*)(Asw + byt);
      }
#pragma unroll
      for (int mt = 0; mt < 4; ++mt)
#pragma unroll
        for (int nt = 0; nt < 4; ++nt)
          acc[mt][nt] = __builtin_amdgcn_mfma_f32_16x16x32_bf16(
              af[mt], bcur[nt], acc[mt][nt], 0, 0, 0);
      __builtin_amdgcn_sched_barrier(0);  // pin pipeline depth to 1 step
#pragma unroll
      for (int nt = 0; nt < 4; ++nt) bcur[nt] = bnxt[nt];
    }
    const int nb = c * 256 + w * 64;
    float biasv[4];
#pragma unroll
    for (int nt = 0; nt < 4; ++nt) biasv[nt] = bias[nb + nt * 16 + l15];
#pragma unroll
    for (int mt = 0; mt < 4; ++mt)
#pragma unroll
      for (int nt = 0; nt < 4; ++nt)
#pragma unroll
        for (int rr = 0; rr < 4; ++rr) acc[mt][nt][rr] += biasv[nt];

    if (joiner) {
      if (c == 3 && w == 3 && l15 == 15) {
#pragma unroll
        for (int mt = 0; mt < 4; ++mt)
#pragma unroll
          for (int rr = 0; rr < 4; ++rr)
            s_blank[mt * 16 + l4 * 4 + rr] = acc[mt][3][rr];
      }
#pragma unroll
      for (int mt = 0; mt < 4; ++mt)
#pragma unroll
        for (int rr = 0; rr < 4; ++rr) {
          int row = mt * 16 + l4 * 4 + rr;
          int tg = s_tgt[row];
          if ((tg >> 8) == c && ((tg >> 6) & 3) == w && (tg & 15) == l15) {
            int ntv = (tg >> 4) & 3;
            float v01 = (ntv & 1) ? acc[mt][1][rr] : acc[mt][0][rr];
            float v23 = (ntv & 1) ? acc[mt][3][rr] : acc[mt][2][rr];
            s_label[row] = (ntv & 2) ? v23 : v01;
          }
        }
    } else {
      if (c == 3 && w == 3 && l15 == 15) {
#pragma unroll
        for (int mt = 0; mt < 4; ++mt)
#pragma unroll
          for (int rr = 0; rr < 4; ++rr)
            s_blank[mt * 16 + l4 * 4 + rr] = acc[mt][3][rr];
      }
#pragma unroll 1
      for (int u = 0; u < 64; ++u) {
        int tgu = s_tgt[u];
        if ((tgu >> 8) == c && ((tgu >> 6) & 3) == w) {
          int ntv = (tgu >> 4) & 3;
          if ((tgu & 15) == l15) {
#pragma unroll
            for (int mt = 0; mt < 4; ++mt)
#pragma unroll
              for (int rr = 0; rr < 4; ++rr) {
                float v01 = (ntv & 1) ? acc[mt][1][rr] : acc[mt][0][rr];
                float v23 = (ntv & 1) ? acc[mt][3][rr] : acc[mt][2][rr];
                float v = (ntv & 2) ? v23 : v01;
                ctc_lab[(g0 + mt * 16 + l4 * 4 + rr) * 64 + u] = v;
              }
          }
        }
      }
    }
#pragma unroll
    for (int mt = 0; mt < 4; ++mt)
#pragma unroll
      for (int rr = 0; rr < 4; ++rr)
        ssum[mt * 4 + rr] += __expf(acc[mt][0][rr]) + __expf(acc[mt][1][rr]) +
                             __expf(acc[mt][2][rr]) + __expf(acc[mt][3][rr]);
  }

#pragma unroll
  for (int ms = 1; ms < 16; ms <<= 1)
#pragma unroll
    for (int j = 0; j < 16; ++j) ssum[j] += __shfl_xor(ssum[j], ms, 64);
  if (l15 == 0) {
#pragma unroll
    for (int j = 0; j < 16; ++j)
      s_psum[w][(j >> 2) * 16 + l4 * 4 + (j & 3)] = ssum[j];
  }
  __syncthreads();

  if (tid < 64) {
    float tot = s_psum[0][tid] + s_psum[1][tid] + s_psum[2][tid] + s_psum[3][tid];
    float lse = __logf(tot);
    if (joiner) {
      int r = r0 + tid;
      int t = r / 65;
      int u = r - t * 65;
      lp_blank[(b * Tn + t) * UP1 + u] = s_blank[tid] - lse;
      if (u < Un) lp_label[(b * Tn + t) * Un + u] = s_label[tid] - lse;
    } else {
      ctc_blank[g0 + tid] = s_blank[tid] - lse;
      ctc_lse[g0 + tid] = lse;
    }
  }
}

// ---------------------------------------------------------------------------
// K3 k_dp: blocks 0-3 RNNT anti-diagonal DP; blocks 4-7 CTC DP.
// DE-PREDICATED RNNT chain: clamped loads + NEG-padding invariant make the
// valid-range masks unnecessary (junk cells stay ~-1e30 exactly in f32 and
// exp(junk - real) underflows to 0, so valid cells are exact). Lane-0 label
// mask folded into the load phase. 8-step register prefetch retained.
// ---------------------------------------------------------------------------
__global__ __launch_bounds__(256) void k_dp(
    const float* __restrict__ lp_blank, const float* __restrict__ lp_label,
    const float* __restrict__ ctc_blank, const float* __restrict__ ctc_lse,
    const float* __restrict__ ctc_lab,
    const int* __restrict__ target,
    const int* __restrict__ flen, const int* __restrict__ tlen,
    float* __restrict__ out) {
  __shared__ float sA[256 * 66];             // RNNT lp_blank[t][u], stride 66
  __shared__ __align__(16) float sB[16384];  // RNNT lp_label / CTC raw labels
  __shared__ float sC[256], sD[256];         // CTC blank / lse
  __shared__ float cT[129];
  const int tid = threadIdx.x;
  const int l = tid & 63;

  if (blockIdx.x < 4) {
    const int b = blockIdx.x;
    for (int i = tid; i < 16640; i += 256) {
      int r = i / 65, cidx = i - r * 65;
      sA[r * 66 + cidx] = lp_blank[b * 16640 + i];
    }
    {
      const f32x4* g2 = (const f32x4*)(lp_label + b * 16384);
      f32x4* s2 = (f32x4*)sB;
      for (int i = tid; i < 4096; i += 256) s2[i] = g2[i];
    }
    __syncthreads();
    if (tid < 64) {
      const int ft = flen[b], tl = tlen[b];
      const int dstar = ft - 1 + tl;
      const bool isown = (l == tl);
      const bool is64 = (tl == 64) && (l == 63);
      const int lc = (l >= 1) ? l - 1 : 0;

#define RLOAD(D0, VB, VL, VB64, VL64)                                          \
  _Pragma("unroll") for (int j = 0; j < 8; ++j) {                              \
    const int d_ = (D0) + j;                                                   \
    const int t_ = d_ - l;                                                     \
    const int tbc_ = (t_ < 1) ? 1 : (t_ > 255 ? 255 : t_);                     \
    const int tcc_ = (t_ < 0) ? 0 : (t_ > 255 ? 255 : t_);                     \
    VB[j] = sA[(tbc_ - 1) * 66 + l];                                           \
    VL[j] = (l == 0) ? NEGF : sB[tcc_ * 64 + lc];                              \
    const int t64_ = d_ - 64;                                                  \
    const int t64b_ = (t64_ < 1) ? 1 : (t64_ > 255 ? 255 : t64_);              \
    const int t64c_ = (t64_ < 0) ? 0 : (t64_ > 255 ? 255 : t64_);              \
    VB64[j] = sA[(t64b_ - 1) * 66 + 64];                                       \
    VL64[j] = sB[t64c_ * 64 + 63];                                             \
  }

      float cvb[8], cvl[8], cvb64[8], cvl64[8];
      RLOAD(1, cvb, cvl, cvb64, cvl64);
      float a = (l == 0) ? 0.0f : NEGF;
      float a64 = NEGF, cap = NEGF;
      for (int d0 = 1; d0 <= 313; d0 += 8) {  // d up to 320 >= 319
        float nvb[8], nvl[8], nvb64[8], nvl64[8];
        RLOAD(d0 + 8, nvb, nvl, nvb64, nvl64);  // prefetch next block
        __builtin_amdgcn_sched_barrier(0);
#pragma unroll
        for (int j = 0; j < 8; ++j) {  // chain: no range predication
          const int d = d0 + j;
          float aleft = shfl_up1(a);
          float up = a + cvb[j];
          float lft = aleft + cvl[j];          // lane 0: cvl = NEGF
          float nw = laddexp(up, lft);
          float up64 = a64 + cvb64[j];
          float nw64 = laddexp(up64, a + cvl64[j]);  // old a = alpha[t64][63]
          a = nw;
          a64 = (l == 63) ? nw64 : a64;
          bool hit = (d == dstar);
          cap = (hit && isown) ? a : cap;
          cap = (hit && is64) ? a64 : cap;
        }
        __builtin_amdgcn_sched_barrier(0);
#pragma unroll
        for (int j = 0; j < 8; ++j) {
          cvb[j] = nvb[j];
          cvl[j] = nvl[j];
          cvb64[j] = nvb64[j];
          cvl64[j] = nvl64[j];
        }
      }
#undef RLOAD
      bool owner = (tl < 64) ? isown : (l == 63);
      if (owner) atomicAdd(out, -0.25f * (cap + sA[(ft - 1) * 66 + tl]));
    }
  } else {
    const int b = blockIdx.x - 4;
    {
      const f32x4* g2 = (const f32x4*)(ctc_lab + b * 16384);
      f32x4* s2 = (f32x4*)sB;
      for (int i = tid; i < 4096; i += 256) s2[i] = g2[i];
      sC[tid] = ctc_blank[b * 256 + tid];
      sD[tid] = ctc_lse[b * 256 + tid];
    }
    __syncthreads();
    if (tid < 64) {
      const int ft = flen[b], tl = tlen[b];
      const int tg = target[b * Un + l];
      const int tgp = (l >= 1) ? target[b * Un + l - 1] : -1;
      const bool skip1 = (l >= 1) && (tg != tgp);

#define CLOAD(T0, EB, E1)                                                      \
  _Pragma("unroll") for (int j = 0; j < 8; ++j) {                              \
    const int tc_ = ((T0) + j > 255) ? 255 : (T0) + j;                         \
    EB[j] = sC[tc_];                                                           \
    E1[j] = sB[tc_ * 64 + l] - sD[tc_];                                        \
  }

      float ceb[8], ce1[8];
      CLOAD(1, ceb, ce1);
      float a0 = (l == 0) ? sC[0] : NEGF;
      float a1 = (l == 0) ? (sB[0] - sD[0]) : NEGF;
      float a2 = NEGF;
      for (int t0 = 1; t0 <= 249; t0 += 8) {  // t up to 256; pad frozen
        float neb[8], ne1[8];
        CLOAD(t0 + 8, neb, ne1);
        __builtin_amdgcn_sched_barrier(0);
#pragma unroll
        for (int j = 0; j < 8; ++j) {
          const int t = t0 + j;
          float pm1 = shfl_up1(a1);
          pm1 = (l == 0) ? NEGF : pm1;
          float n0 = ceb[j] + laddexp(a0, pm1);
          float n1 = ce1[j] + laddexp3(a1, a0, skip1 ? pm1 : NEGF);
          float n2 = ceb[j] + laddexp(a2, a1);
          bool run = (t < ft);
          a0 = run ? n0 : a0;
          a1 = run ? n1 : a1;
          a2 = (run && (l == 63)) ? n2 : a2;
        }
        __builtin_amdgcn_sched_barrier(0);
#pragma unroll
        for (int j = 0; j < 8; ++j) {
          ceb[j] = neb[j];
          ce1[j] = ne1[j];
        }
      }
#undef CLOAD
      cT[2 * l] = a0;
      cT[2 * l + 1] = a1;
      if (l == 63) cT[128] = a2;
      __builtin_amdgcn_s_waitcnt(0);  // intra-wave lgkm drain before readback
      if (l == 0) {
        int sl = 2 * tl;
        float ll = laddexp(cT[sl], cT[sl - 1]);
        float lb = (ll < NEGF * 0.5f) ? 0.0f : -ll;
        atomicAdd(out, CTCW * 0.25f * lb);
      }
    }
  }
}

// ---------------------------------------------------------------------------
extern "C" void kernel_launch(void* const* d_in, const int* in_sizes, int n_in,
                              void* d_out, int out_size, void* d_ws, size_t ws_size,
                              hipStream_t stream) {
  (void)in_sizes; (void)n_in; (void)out_size; (void)ws_size;
  const float* x_enc = (const float*)d_in[0];
  const float* x_dec = (const float*)d_in[1];
  const float* W_enc = (const float*)d_in[2];
  const float* b_enc = (const float*)d_in[3];
  const float* W_dec = (const float*)d_in[4];
  const float* b_dec = (const float*)d_in[5];
  const float* W_out = (const float*)d_in[6];
  const float* b_out = (const float*)d_in[7];
  const float* W_ctc = (const float*)d_in[8];
  const float* b_ctc = (const float*)d_in[9];
  const int* target = (const int*)d_in[10];
  const int* flen = (const int*)d_in[11];
  const int* tlen = (const int*)d_in[12];

  float* ws = (float*)d_ws;
  float* enc_lin = ws;                    // 262144
  float* dec_lin = ws + 262144;           // 66560
  float* lp_blank = ws + 328704;          // 66560
  float* lp_label = ws + 395264;          // 65536
  float* ctc_blank = ws + 460800;         // 1024
  float* ctc_lse = ws + 461824;           // 1024
  float* ctc_lab = ws + 462848;           // 65536
  unsigned short* Wt_out = (unsigned short*)(ws + 528384);  // 262144 bf16 (tiled)
  unsigned short* Wt_ctc = Wt_out + 262144;                 // 262144 bf16 (tiled)
  unsigned short* Wt_enc = (unsigned short*)lp_blank;       // 65536 bf16
  unsigned short* Wt_dec = (unsigned short*)lp_label;       // 65536 bf16
  float* out = (float*)d_out;

  k_prep<<<dim3(160), dim3(256), 0, stream>>>(
      W_enc, W_dec, W_out, W_ctc, Wt_enc, Wt_dec, Wt_out, Wt_ctc, out);
  k_lin<<<dim3(21), dim3(256), 0, stream>>>(
      x_enc, x_dec, Wt_enc, b_enc, Wt_dec, b_dec, enc_lin, dec_lin);
  k_join2<<<dim3(1056), dim3(256), 0, stream>>>(
      enc_lin, dec_lin, Wt_out, b_out, x_enc, Wt_ctc, b_ctc, target,
      lp_blank, lp_label, ctc_blank, ctc_lse, ctc_lab);
  k_dp<<<dim3(8), dim3(64 * 4), 0, stream>>>(
      lp_blank, lp_label, ctc_blank, ctc_lse, ctc_lab, target, flen, tlen, out);
}

// Round 10
// 122.581 us; speedup vs baseline: 1.7841x; 1.2224x over previous
//
#include <hip/hip_runtime.h>
#include <hip/hip_bf16.h>

#define Bn 4
#define Tn 256
#define Un 64
#define UP1 65
#define Vn 1024
#define Dn 256
#define Hn 256
#define BLANKC 1023
#define NEGF (-1.0e30f)
#define CTCW 0.3f
#define R2E 1.4426950408889634f  // 1/ln2
#define LN2 0.6931471805599453f

typedef __attribute__((ext_vector_type(8))) short short8;
typedef __attribute__((ext_vector_type(4))) float f32x4;
typedef __attribute__((ext_vector_type(4))) unsigned int u32x4;

static __device__ __forceinline__ unsigned short f2bf(float f) {
  unsigned int u = __float_as_uint(f);
  u += 0x7FFFu + ((u >> 16) & 1u);
  return (unsigned short)(u >> 16);
}
static __device__ __forceinline__ unsigned int pack2bf(float a, float b) {
  return (unsigned int)f2bf(a) | ((unsigned int)f2bf(b) << 16);
}
static __device__ __forceinline__ float ftanh(float x) {
  float e = __expf(2.0f * x);
  return 1.0f - 2.0f / (e + 1.0f);
}
static __device__ __forceinline__ float ex2(float x) {
  return __builtin_amdgcn_exp2f(x);
}
static __device__ __forceinline__ float lg2(float x) {
  return __builtin_amdgcn_logf(x);
}
// base-2 logaddexp; safe for +-1e30 garbage magnitudes (max-form).
static __device__ __forceinline__ float laddexp2_(float x, float y) {
  float m = fmaxf(x, y);
  float d = y - x;
  return m + lg2(1.0f + ex2(-fabsf(d)));
}
static __device__ __forceinline__ float laddexp3_2(float a, float b, float c) {
  float m = fmaxf(fmaxf(a, b), c);
  return m + lg2(ex2(a - m) + ex2(b - m) + ex2(c - m));
}
// lane i <- lane i-1 (lane 0 gets 0; callers mask lane 0). DPP wave_shr:1.
static __device__ __forceinline__ float shfl_up1(float x) {
  int r = __builtin_amdgcn_update_dpp(0, __float_as_int(x), 0x138, 0xF, 0xF, false);
  return __int_as_float(r);
}

// ---------------------------------------------------------------------------
// K1 k_prep: W_out/W_ctc -> step-tiled bf16 layout Wt2[s=(c,ks)][sub][col][8k];
// W_enc/W_dec -> flat bf16 transpose. Zeroes d_out.
// ---------------------------------------------------------------------------
__global__ __launch_bounds__(256) void k_prep(
    const float* __restrict__ W_enc, const float* __restrict__ W_dec,
    const float* __restrict__ W_out, const float* __restrict__ W_ctc,
    unsigned short* __restrict__ Wt_enc, unsigned short* __restrict__ Wt_dec,
    unsigned short* __restrict__ Wt_out, unsigned short* __restrict__ Wt_ctc,
    float* __restrict__ out) {
  const int blk = blockIdx.x, tid = threadIdx.x;
  if (blk == 0 && tid == 0) out[0] = 0.0f;
  __shared__ float tilebuf[64][65];
  if (blk < 128) {
    const float* Wsrc = (blk < 64) ? W_out : W_ctc;
    unsigned short* Wd = (blk < 64) ? Wt_out : Wt_ctc;
    const int tt = blk & 63;
    const int k0 = (tt & 3) * 64, v0 = (tt >> 2) * 64;
#pragma unroll
    for (int rep = 0; rep < 16; ++rep) {
      int e = rep * 256 + tid;
      int rr = e >> 6, cc = e & 63;  // rr: k-off, cc: n-off
      tilebuf[rr][cc] = Wsrc[(k0 + rr) * 1024 + (v0 + cc)];
    }
    __syncthreads();
#pragma unroll
    for (int rep = 0; rep < 16; ++rep) {
      int e = rep * 256 + tid;
      int nn = e >> 6, kk = e & 63;
      int n = v0 + nn, k = k0 + kk;
      int c = n >> 8, col = n & 255;
      int ks = k >> 5, sub = (k >> 3) & 3, k7 = k & 7;
      Wd[(c * 8 + ks) * 8192 + sub * 2048 + col * 8 + k7] = f2bf(tilebuf[kk][nn]);
    }
  } else {
    const float* Wsrc = (blk < 144) ? W_enc : W_dec;
    unsigned short* Wd = (blk < 144) ? Wt_enc : Wt_dec;
    const int tt = (blk - 128) & 15;
    const int k0 = (tt & 3) * 64, v0 = (tt >> 2) * 64;
#pragma unroll
    for (int rep = 0; rep < 16; ++rep) {
      int e = rep * 256 + tid;
      int rr = e >> 6, cc = e & 63;
      tilebuf[rr][cc] = Wsrc[(k0 + rr) * 256 + (v0 + cc)];
    }
    __syncthreads();
#pragma unroll
    for (int rep = 0; rep < 16; ++rep) {
      int e = rep * 256 + tid;
      int rr = e >> 6, cc = e & 63;
      Wd[(v0 + rr) * 256 + (k0 + cc)] = f2bf(tilebuf[cc][rr]);
    }
  }
}

// ---------------------------------------------------------------------------
// K1b k_lin: enc_lin / dec_lin via MFMA (tiny).
// ---------------------------------------------------------------------------
__global__ __launch_bounds__(256) void k_lin(
    const float* __restrict__ x_enc, const float* __restrict__ x_dec,
    const unsigned short* __restrict__ Wt_enc, const float* __restrict__ b_enc,
    const unsigned short* __restrict__ Wt_dec, const float* __restrict__ b_dec,
    float* __restrict__ enc_lin, float* __restrict__ dec_lin) {
  __shared__ __align__(16) char Asw[64 * 512];
  const int tid = threadIdx.x;
  const int w = tid >> 6, l = tid & 63;
  const int l15 = l & 15, l4 = l >> 4;
  const bool enc = blockIdx.x < 16;
  const int m0 = enc ? blockIdx.x * 64 : (blockIdx.x - 16) * 64;
  const int Mlim = enc ? 1024 : 260;
  const float* xp = enc ? x_enc : x_dec;
  const unsigned short* Wt = enc ? Wt_enc : Wt_dec;
  const float* bias = enc ? b_enc : b_dec;
  float* outp = enc ? enc_lin : dec_lin;

#pragma unroll
  for (int it = 0; it < 8; ++it) {
    int e = (it << 8) + tid;
    int i = e >> 5;
    int k0 = (e & 31) << 3;
    int r = m0 + i;
    if (r > Mlim - 1) r = Mlim - 1;
    const float* sp = xp + r * 256 + k0;
    f32x4 e0 = *(const f32x4*)sp;
    f32x4 e1 = *(const f32x4*)(sp + 4);
    u32x4 pv;
    pv[0] = pack2bf(e0[0], e0[1]);
    pv[1] = pack2bf(e0[2], e0[3]);
    pv[2] = pack2bf(e1[0], e1[1]);
    pv[3] = pack2bf(e1[2], e1[3]);
    int byt = (i << 9) + (k0 << 1);
    byt ^= (i & 7) << 4;
    *(u32x4*)(Asw + byt) = pv;
  }
  __syncthreads();

  const int nb = w * 64;
  f32x4 acc[4][4] = {};
#pragma unroll
  for (int ks = 0; ks < 8; ++ks) {
    int k = ks * 32 + l4 * 8;
    short8 af[4];
#pragma unroll
    for (int mt = 0; mt < 4; ++mt) {
      int i = mt * 16 + l15;
      int byt = (i << 9) + (k << 1);
      byt ^= (i & 7) << 4;
      af[mt] = *(const short8*)(Asw + byt);
    }
    short8 bfr[4];
#pragma unroll
    for (int nt = 0; nt < 4; ++nt) {
      int n = nb + nt * 16 + l15;
      bfr[nt] = *(const short8*)(Wt + n * 256 + k);
    }
#pragma unroll
    for (int mt = 0; mt < 4; ++mt)
#pragma unroll
      for (int nt = 0; nt < 4; ++nt)
        acc[mt][nt] = __builtin_amdgcn_mfma_f32_16x16x32_bf16(
            af[mt], bfr[nt], acc[mt][nt], 0, 0, 0);
  }
  float biasv[4];
#pragma unroll
  for (int nt = 0; nt < 4; ++nt) biasv[nt] = bias[nb + nt * 16 + l15];
#pragma unroll
  for (int mt = 0; mt < 4; ++mt)
#pragma unroll
    for (int rr = 0; rr < 4; ++rr) {
      int row = m0 + mt * 16 + l4 * 4 + rr;
      if (row < Mlim) {
#pragma unroll
        for (int nt = 0; nt < 4; ++nt)
          outp[row * 256 + nb + nt * 16 + l15] = acc[mt][nt][rr] + biasv[nt];
      }
    }
}

// ---------------------------------------------------------------------------
// K2 merged: blocks 0-15 = CTC head; blocks 16-1055 = joiner.
// Barrier-free K-loop with DEPTH-2 even/odd register pipeline: step s
// computes on bE/bO and reloads the same set with step s+2 (no copies,
// static roles). Loads fly ~2 steps (~300+ cyc) before consumption,
// covering L2 latency (the R9 stall).
// ---------------------------------------------------------------------------
__global__ __launch_bounds__(256) void k_join2(
    const float* __restrict__ enc_lin, const float* __restrict__ dec_lin,
    const unsigned short* __restrict__ Wt_out, const float* __restrict__ b_out,
    const float* __restrict__ x_enc,
    const unsigned short* __restrict__ Wt_ctc, const float* __restrict__ b_ctc,
    const int* __restrict__ target,
    float* __restrict__ lp_blank, float* __restrict__ lp_label,
    float* __restrict__ ctc_blank, float* __restrict__ ctc_lse,
    float* __restrict__ ctc_lab) {
  __shared__ __align__(16) char Asw[64 * 512];    // 32KB A tile
  __shared__ float s_psum[4][64];
  __shared__ float s_blank[64], s_label[64];
  __shared__ int s_tgt[64];

  const int tid = threadIdx.x;
  const int w = tid >> 6, l = tid & 63;
  const int l15 = l & 15, l4 = l >> 4;

  const bool joiner = blockIdx.x >= 16;
  const unsigned short* Wt = joiner ? Wt_out : Wt_ctc;
  const float* bias = joiner ? b_out : b_ctc;

  // B base: step s, col = w*64 + nt*16 + l15, sub = l4.
  const unsigned short* tb = Wt + l4 * 2048 + (w * 64 + l15) * 8;

  short8 bE[4], bO[4];
#define LOADB(REG, S)                                                          \
  {                                                                            \
    const unsigned short* p_ = tb + (S)*8192;                                  \
    _Pragma("unroll") for (int nt = 0; nt < 4; ++nt)                           \
        REG[nt] = *(const short8*)(p_ + nt * 128);                             \
  }
  LOADB(bE, 0)
  LOADB(bO, 1)

  int b, r0 = 0, g0 = 0;
  if (joiner) {
    const int bid = blockIdx.x - 16;
    b = bid / 260;
    r0 = (bid % 260) * 64;
#pragma unroll
    for (int it = 0; it < 8; ++it) {
      int e = (it << 8) + tid;
      int i = e >> 5;
      int k0 = (e & 31) << 3;
      int r = r0 + i;
      int t = r / 65;
      int u = r - t * 65;
      const float* ep = enc_lin + ((b * Tn + t) * Hn + k0);
      const float* dp = dec_lin + ((b * UP1 + u) * Hn + k0);
      f32x4 e0 = *(const f32x4*)ep;
      f32x4 e1 = *(const f32x4*)(ep + 4);
      f32x4 d0 = *(const f32x4*)dp;
      f32x4 d1 = *(const f32x4*)(dp + 4);
      u32x4 pv;
      pv[0] = pack2bf(ftanh(e0[0] + d0[0]), ftanh(e0[1] + d0[1]));
      pv[1] = pack2bf(ftanh(e0[2] + d0[2]), ftanh(e0[3] + d0[3]));
      pv[2] = pack2bf(ftanh(e1[0] + d1[0]), ftanh(e1[1] + d1[1]));
      pv[3] = pack2bf(ftanh(e1[2] + d1[2]), ftanh(e1[3] + d1[3]));
      int byt = (i << 9) + (k0 << 1);
      byt ^= (i & 7) << 4;
      *(u32x4*)(Asw + byt) = pv;
    }
    if (tid < 64) {
      int u = (r0 + tid) % 65;
      s_tgt[tid] = (u < Un) ? target[b * Un + u] : -1;
    }
  } else {
    g0 = blockIdx.x * 64;
    b = g0 >> 8;
#pragma unroll
    for (int it = 0; it < 8; ++it) {
      int e = (it << 8) + tid;
      int i = e >> 5;
      int k0 = (e & 31) << 3;
      const float* sp = x_enc + (g0 + i) * Dn + k0;
      f32x4 e0 = *(const f32x4*)sp;
      f32x4 e1 = *(const f32x4*)(sp + 4);
      u32x4 pv;
      pv[0] = pack2bf(e0[0], e0[1]);
      pv[1] = pack2bf(e0[2], e0[3]);
      pv[2] = pack2bf(e1[0], e1[1]);
      pv[3] = pack2bf(e1[2], e1[3]);
      int byt = (i << 9) + (k0 << 1);
      byt ^= (i & 7) << 4;
      *(u32x4*)(Asw + byt) = pv;
    }
    if (tid < 64) s_tgt[tid] = target[b * Un + tid];
  }
  __syncthreads();  // A tile + s_tgt ready; the ONLY pre-epilogue barrier

  float ssum[16];
#pragma unroll
  for (int j = 0; j < 16; ++j) ssum[j] = 0.0f;

#define MFMASTEP(REG, KS)                                                      \
  {                                                                            \
    const int k_ = (KS)*32 + l4 * 8;                                           \
    _Pragma("unroll") for (int mt = 0; mt < 4; ++mt) {                         \
      int i_ = mt * 16 + l15;                                                  \
      int byt_ = ((i_ << 9) + (k_ << 1)) ^ ((i_ & 7) << 4);                    \
      short8 af_ = *(const short8*)(Asw + byt_);                               \
      _Pragma("unroll") for (int nt = 0; nt < 4; ++nt)                         \
          acc[mt][nt] = __builtin_amdgcn_mfma_f32_16x16x32_bf16(               \
              af_, REG[nt], acc[mt][nt], 0, 0, 0);                             \
    }                                                                          \
  }

#pragma unroll 1
  for (int c = 0; c < 4; ++c) {
    f32x4 acc[4][4] = {};
#pragma unroll
    for (int ks = 0; ks < 8; ks += 2) {
      const int s = c * 8 + ks;
      MFMASTEP(bE, ks)
      LOADB(bE, (s + 2 < 32) ? s + 2 : 31)  // reload even set, 2 ahead
      __builtin_amdgcn_sched_barrier(0);
      MFMASTEP(bO, ks + 1)
      LOADB(bO, (s + 3 < 32) ? s + 3 : 31)  // reload odd set, 2 ahead
      __builtin_amdgcn_sched_barrier(0);
    }
    const int nb = c * 256 + w * 64;
    float biasv[4];
#pragma unroll
    for (int nt = 0; nt < 4; ++nt) biasv[nt] = bias[nb + nt * 16 + l15];
#pragma unroll
    for (int mt = 0; mt < 4; ++mt)
#pragma unroll
      for (int nt = 0; nt < 4; ++nt)
#pragma unroll
        for (int rr = 0; rr < 4; ++rr) acc[mt][nt][rr] += biasv[nt];

    if (joiner) {
      if (c == 3 && w == 3 && l15 == 15) {
#pragma unroll
        for (int mt = 0; mt < 4; ++mt)
#pragma unroll
          for (int rr = 0; rr < 4; ++rr)
            s_blank[mt * 16 + l4 * 4 + rr] = acc[mt][3][rr];
      }
#pragma unroll
      for (int mt = 0; mt < 4; ++mt)
#pragma unroll
        for (int rr = 0; rr < 4; ++rr) {
          int row = mt * 16 + l4 * 4 + rr;
          int tg = s_tgt[row];
          if ((tg >> 8) == c && ((tg >> 6) & 3) == w && (tg & 15) == l15) {
            int ntv = (tg >> 4) & 3;
            float v01 = (ntv & 1) ? acc[mt][1][rr] : acc[mt][0][rr];
            float v23 = (ntv & 1) ? acc[mt][3][rr] : acc[mt][2][rr];
            s_label[row] = (ntv & 2) ? v23 : v01;
          }
        }
    } else {
      if (c == 3 && w == 3 && l15 == 15) {
#pragma unroll
        for (int mt = 0; mt < 4; ++mt)
#pragma unroll
          for (int rr = 0; rr < 4; ++rr)
            s_blank[mt * 16 + l4 * 4 + rr] = acc[mt][3][rr];
      }
#pragma unroll 1
      for (int u = 0; u < 64; ++u) {
        int tgu = s_tgt[u];
        if ((tgu >> 8) == c && ((tgu >> 6) & 3) == w) {
          int ntv = (tgu >> 4) & 3;
          if ((tgu & 15) == l15) {
#pragma unroll
            for (int mt = 0; mt < 4; ++mt)
#pragma unroll
              for (int rr = 0; rr < 4; ++rr) {
                float v01 = (ntv & 1) ? acc[mt][1][rr] : acc[mt][0][rr];
                float v23 = (ntv & 1) ? acc[mt][3][rr] : acc[mt][2][rr];
                float v = (ntv & 2) ? v23 : v01;
                ctc_lab[(g0 + mt * 16 + l4 * 4 + rr) * 64 + u] = v;
              }
          }
        }
      }
    }
#pragma unroll
    for (int mt = 0; mt < 4; ++mt)
#pragma unroll
      for (int rr = 0; rr < 4; ++rr)
        ssum[mt * 4 + rr] += __expf(acc[mt][0][rr]) + __expf(acc[mt][1][rr]) +
                             __expf(acc[mt][2][rr]) + __expf(acc[mt][3][rr]);
  }
#undef MFMASTEP
#undef LOADB

#pragma unroll
  for (int ms = 1; ms < 16; ms <<= 1)
#pragma unroll
    for (int j = 0; j < 16; ++j) ssum[j] += __shfl_xor(ssum[j], ms, 64);
  if (l15 == 0) {
#pragma unroll
    for (int j = 0; j < 16; ++j)
      s_psum[w][(j >> 2) * 16 + l4 * 4 + (j & 3)] = ssum[j];
  }
  __syncthreads();

  if (tid < 64) {
    float tot = s_psum[0][tid] + s_psum[1][tid] + s_psum[2][tid] + s_psum[3][tid];
    float lse = __logf(tot);
    if (joiner) {
      int r = r0 + tid;
      int t = r / 65;
      int u = r - t * 65;
      lp_blank[(b * Tn + t) * UP1 + u] = s_blank[tid] - lse;
      if (u < Un) lp_label[(b * Tn + t) * Un + u] = s_label[tid] - lse;
    } else {
      ctc_blank[g0 + tid] = s_blank[tid] - lse;
      ctc_lse[g0 + tid] = lse;
    }
  }
}

// ---------------------------------------------------------------------------
// K3 k_dp: blocks 0-3 RNNT anti-diagonal DP; blocks 4-7 CTC DP.
// BASE-2 LOG SPACE: inputs pre-scaled by 1/ln2 during the bulk LDS preload,
// chain uses native v_exp_f32/v_log_f32 (base-2) with the -|d| folded into
// exp2 input modifiers; result scaled by ln2 once at the end. Max-form is
// exact for +-1e30 garbage (no cancellation). 8-step register prefetch.
// ---------------------------------------------------------------------------
__global__ __launch_bounds__(256) void k_dp(
    const float* __restrict__ lp_blank, const float* __restrict__ lp_label,
    const float* __restrict__ ctc_blank, const float* __restrict__ ctc_lse,
    const float* __restrict__ ctc_lab,
    const int* __restrict__ target,
    const int* __restrict__ flen, const int* __restrict__ tlen,
    float* __restrict__ out) {
  __shared__ float sA[256 * 66];             // RNNT lp_blank[t][u]/ln2, stride 66
  __shared__ __align__(16) float sB[16384];  // RNNT lp_label/ln2 ; CTC raw/ln2
  __shared__ float sC[256], sD[256];         // CTC blank/ln2, lse/ln2
  __shared__ float cT[129];
  const int tid = threadIdx.x;
  const int l = tid & 63;

  if (blockIdx.x < 4) {
    const int b = blockIdx.x;
    for (int i = tid; i < 16640; i += 256) {
      int r = i / 65, cidx = i - r * 65;
      sA[r * 66 + cidx] = lp_blank[b * 16640 + i] * R2E;
    }
    for (int i = tid; i < 16384; i += 256) sB[i] = lp_label[b * 16384 + i] * R2E;
    __syncthreads();
    if (tid < 64) {
      const int ft = flen[b], tl = tlen[b];
      const int dstar = ft - 1 + tl;
      const bool isown = (l == tl);
      const bool is64 = (tl == 64) && (l == 63);
      const int lc = (l >= 1) ? l - 1 : 0;

#define RLOAD(D0, VB, VL, VB64, VL64)                                          \
  _Pragma("unroll") for (int j = 0; j < 8; ++j) {                              \
    const int d_ = (D0) + j;                                                   \
    const int t_ = d_ - l;                                                     \
    const int tbc_ = (t_ < 1) ? 1 : (t_ > 255 ? 255 : t_);                     \
    const int tcc_ = (t_ < 0) ? 0 : (t_ > 255 ? 255 : t_);                     \
    VB[j] = sA[(tbc_ - 1) * 66 + l];                                           \
    VL[j] = (l == 0) ? NEGF : sB[tcc_ * 64 + lc];                              \
    const int t64_ = d_ - 64;                                                  \
    const int t64b_ = (t64_ < 1) ? 1 : (t64_ > 255 ? 255 : t64_);              \
    const int t64c_ = (t64_ < 0) ? 0 : (t64_ > 255 ? 255 : t64_);              \
    VB64[j] = sA[(t64b_ - 1) * 66 + 64];                                       \
    VL64[j] = sB[t64c_ * 64 + 63];                                             \
  }

      float cvb[8], cvl[8], cvb64[8], cvl64[8];
      RLOAD(1, cvb, cvl, cvb64, cvl64);
      float a = (l == 0) ? 0.0f : NEGF;
      float a64 = NEGF, cap = NEGF;
      for (int d0 = 1; d0 <= 313; d0 += 8) {  // d up to 320 >= 319
        float nvb[8], nvl[8], nvb64[8], nvl64[8];
        RLOAD(d0 + 8, nvb, nvl, nvb64, nvl64);  // prefetch next block
        __builtin_amdgcn_sched_barrier(0);
#pragma unroll
        for (int j = 0; j < 8; ++j) {  // base-2 chain, no range predication
          const int d = d0 + j;
          float aleft = shfl_up1(a);
          float x = a + cvb[j];
          float y = aleft + cvl[j];            // lane 0: cvl = NEGF
          float nw = laddexp2_(x, y);
          float nw64 = laddexp2_(a64 + cvb64[j], a + cvl64[j]);  // old a
          a = nw;
          a64 = (l == 63) ? nw64 : a64;
          bool hit = (d == dstar);
          cap = (hit && isown) ? a : cap;
          cap = (hit && is64) ? a64 : cap;
        }
        __builtin_amdgcn_sched_barrier(0);
#pragma unroll
        for (int j = 0; j < 8; ++j) {
          cvb[j] = nvb[j];
          cvl[j] = nvl[j];
          cvb64[j] = nvb64[j];
          cvl64[j] = nvl64[j];
        }
      }
#undef RLOAD
      bool owner = (tl < 64) ? isown : (l == 63);
      if (owner)
        atomicAdd(out, -0.25f * LN2 * (cap + sA[(ft - 1) * 66 + tl]));
    }
  } else {
    const int b = blockIdx.x - 4;
    for (int i = tid; i < 16384; i += 256) sB[i] = ctc_lab[b * 16384 + i] * R2E;
    sC[tid] = ctc_blank[b * 256 + tid] * R2E;
    sD[tid] = ctc_lse[b * 256 + tid] * R2E;
    __syncthreads();
    if (tid < 64) {
      const int ft = flen[b], tl = tlen[b];
      const int tg = target[b * Un + l];
      const int tgp = (l >= 1) ? target[b * Un + l - 1] : -1;
      const bool skip1 = (l >= 1) && (tg != tgp);

#define CLOAD(T0, EB, E1)                                                      \
  _Pragma("unroll") for (int j = 0; j < 8; ++j) {                              \
    const int tc_ = ((T0) + j > 255) ? 255 : (T0) + j;                         \
    EB[j] = sC[tc_];                                                           \
    E1[j] = sB[tc_ * 64 + l] - sD[tc_];                                        \
  }

      float ceb[8], ce1[8];
      CLOAD(1, ceb, ce1);
      float a0 = (l == 0) ? sC[0] : NEGF;
      float a1 = (l == 0) ? (sB[0] - sD[0]) : NEGF;
      float a2 = NEGF;
      for (int t0 = 1; t0 <= 249; t0 += 8) {  // t up to 256; pad frozen
        float neb[8], ne1[8];
        CLOAD(t0 + 8, neb, ne1);
        __builtin_amdgcn_sched_barrier(0);
#pragma unroll
        for (int j = 0; j < 8; ++j) {
          const int t = t0 + j;
          float pm1 = shfl_up1(a1);
          pm1 = (l == 0) ? NEGF : pm1;
          float n0 = ceb[j] + laddexp2_(a0, pm1);
          float n1 = ce1[j] + laddexp3_2(a1, a0, skip1 ? pm1 : NEGF);
          float n2 = ceb[j] + laddexp2_(a2, a1);
          bool run = (t < ft);
          a0 = run ? n0 : a0;
          a1 = run ? n1 : a1;
          a2 = (run && (l == 63)) ? n2 : a2;
        }
        __builtin_amdgcn_sched_barrier(0);
#pragma unroll
        for (int j = 0; j < 8; ++j) {
          ceb[j] = neb[j];
          ce1[j] = ne1[j];
        }
      }
#undef CLOAD
      cT[2 * l] = a0;
      cT[2 * l + 1] = a1;
      if (l == 63) cT[128] = a2;
      __builtin_amdgcn_s_waitcnt(0);  // intra-wave lgkm drain before readback
      if (l == 0) {
        int sl = 2 * tl;
        float ll = laddexp2_(cT[sl], cT[sl - 1]);  // base-2 units
        float lb = (ll < NEGF * 0.5f * R2E) ? 0.0f : -ll;
        atomicAdd(out, CTCW * 0.25f * LN2 * lb);
      }
    }
  }
}

// ---------------------------------------------------------------------------
extern "C" void kernel_launch(void* const* d_in, const int* in_sizes, int n_in,
                              void* d_out, int out_size, void* d_ws, size_t ws_size,
                              hipStream_t stream) {
  (void)in_sizes; (void)n_in; (void)out_size; (void)ws_size;
  const float* x_enc = (const float*)d_in[0];
  const float* x_dec = (const float*)d_in[1];
  const float* W_enc = (const float*)d_in[2];
  const float* b_enc = (const float*)d_in[3];
  const float* W_dec = (const float*)d_in[4];
  const float* b_dec = (const float*)d_in[5];
  const float* W_out = (const float*)d_in[6];
  const float* b_out = (const float*)d_in[7];
  const float* W_ctc = (const float*)d_in[8];
  const float* b_ctc = (const float*)d_in[9];
  const int* target = (const int*)d_in[10];
  const int* flen = (const int*)d_in[11];
  const int* tlen = (const int*)d_in[12];

  float* ws = (float*)d_ws;
  float* enc_lin = ws;                    // 262144
  float* dec_lin = ws + 262144;           // 66560
  float* lp_blank = ws + 328704;          // 66560
  float* lp_label = ws + 395264;          // 65536
  float* ctc_blank = ws + 460800;         // 1024
  float* ctc_lse = ws + 461824;           // 1024
  float* ctc_lab = ws + 462848;           // 65536
  unsigned short* Wt_out = (unsigned short*)(ws + 528384);  // 262144 bf16 (tiled)
  unsigned short* Wt_ctc = Wt_out + 262144;                 // 262144 bf16 (tiled)
  unsigned short* Wt_enc = (unsigned short*)lp_blank;       // 65536 bf16
  unsigned short* Wt_dec = (unsigned short*)lp_label;       // 65536 bf16
  float* out = (float*)d_out;

  k_prep<<<dim3(160), dim3(256), 0, stream>>>(
      W_enc, W_dec, W_out, W_ctc, Wt_enc, Wt_dec, Wt_out, Wt_ctc, out);
  k_lin<<<dim3(21), dim3(256), 0, stream>>>(
      x_enc, x_dec, Wt_enc, b_enc, Wt_dec, b_dec, enc_lin, dec_lin);
  k_join2<<<dim3(1056), dim3(256), 0, stream>>>(
      enc_lin, dec_lin, Wt_out, b_out, x_enc, Wt_ctc, b_ctc, target,
      lp_blank, lp_label, ctc_blank, ctc_lse, ctc_lab);
  k_dp<<<dim3(8), dim3(64 * 4), 0, stream>>>(
      lp_blank, lp_label, ctc_blank, ctc_lse, ctc_lab, target, flen, tlen, out);
}